// Round 11
// baseline (774.556 us; speedup 1.0000x reference)
//
#include <hip/hip_runtime.h>
#include <stdint.h>
#include <math.h>

// Problem constants (match reference)
#define EDGES 563200
#define NNODES 17600    // B*(NW+NS)
#define OUT0SZ 2640000  // 17600*150
#define MROWS 64000     // 1600 sentences * 40 positions
#define MPAD  64016     // + zero pad rows for window overhang
#define KSTRIDE 2112    // B pack row stride (halfs)

typedef _Float16 h2 __attribute__((ext_vector_type(2)));
typedef _Float16 h4 __attribute__((ext_vector_type(4)));
typedef _Float16 v8h __attribute__((ext_vector_type(8)));
typedef float v4f __attribute__((ext_vector_type(4)));

__device__ __forceinline__ float sigm(float x){ return 1.f / (1.f + expf(-x)); }

__device__ __forceinline__ float fdot2_(h2 a, h2 b, float c){
#if __has_builtin(__builtin_amdgcn_fdot2)
  return __builtin_amdgcn_fdot2(a, b, c, false);
#else
  return c + (float)a.x * (float)b.x + (float)a.y * (float)b.y;
#endif
}

// async global->LDS, 16B per lane; dest = wave-uniform base + lane*16
__device__ __forceinline__ void stage16(const char* g, char* lds_base, int lane){
#if __has_builtin(__builtin_amdgcn_global_load_lds)
  __builtin_amdgcn_global_load_lds(
      (const __attribute__((address_space(1))) void*)g,
      (__attribute__((address_space(3))) void*)lds_base, 16, 0, 0);
#else
  uint4 v = *(const uint4*)g;
  *(uint4*)(lds_base + lane * 16) = v;
#endif
}

// ---------------- sentlen + glen + rowmap, one block ------------------------
__global__ __launch_bounds__(1024)
void gcnk_prep2(const int* __restrict__ sx, int* __restrict__ sentlen,
                int* __restrict__ glen_g, int* __restrict__ rowmap){
  __shared__ int sg[32];
  int tid = threadIdx.x;
  for (int i = tid; i < 1600; i += 1024){
    int c = 0;
    for (int j = 0; j < 40; j++) c += (sx[i * 40 + j] != 0);
    sentlen[i] = c;
  }
  if (tid < 32){
    int c = 0;
    for (int s = 0; s < 50; s++) c += (sx[tid * 2000 + s * 40] != 0);
    glen_g[tid] = c; sg[tid] = c;
  }
  __syncthreads();
  for (int i = tid; i < 1600; i += 1024){
    int b = i / 50, t = i - b * 50, g = sg[b];
    rowmap[i] = b * 50 + ((t < g) ? (g - 1 - t) : t);
  }
}

// ---------------- merged prep: postab | bpack | whhpack x2 | zero x2 | embw -
__global__ __launch_bounds__(256)
void gcnk_mergedprep(float* __restrict__ pos,
                     const float* w2, const float* w3, const float* w4,
                     const float* w5, const float* w6, const float* w7,
                     const float* c2, const float* c3, const float* c4,
                     const float* c5, const float* c6, const float* c7,
                     _Float16* __restrict__ Bp, float* __restrict__ bias_p,
                     const float* __restrict__ whh0, _Float16* __restrict__ wpad0,
                     const float* __restrict__ whh1, _Float16* __restrict__ wpad1,
                     unsigned int* __restrict__ ngram_u, unsigned int* __restrict__ ecnt_u,
                     const int* __restrict__ x, const float* __restrict__ tab,
                     float4* __restrict__ out1){
  int blk = blockIdx.x, tid = threadIdx.x;
  if (blk < 602){
    int idx = blk * 256 + tid;
    if (idx >= 513 * 300) return;
    int p = idx / 300, i = idx - p * 300;
    float v = 0.f;
    if (p != 0){
      double expo = (double)(2 * (i / 2)) / 300.0;
      double ang = (double)p / pow(10000.0, expo);
      v = (float)((i & 1) ? cos(ang) : sin(ang));
    }
    pos[idx] = v;
  } else if (blk < 3242){
    int idx = (blk - 602) * 256 + tid;
    if (idx < 2 * 160 * KSTRIDE){
      int n = idx / KSTRIDE, kk = idx - n * KSTRIDE;
      int g = n / 160, c = n - g * 160;
      _Float16 v = (_Float16)0.f;
      if (c < 150){
        int H = 3 * g + 2 + c / 50, o = c % 50;
        if (kk < 300 * H){
          const float* w;
          switch (H){ case 2: w = w2; break; case 3: w = w3; break;
                      case 4: w = w4; break; case 5: w = w5; break;
                      case 6: w = w6; break; default: w = w7; break; }
          v = (_Float16)w[o * 300 * H + kk];
        }
      }
      Bp[idx] = v;
    }
    if (idx < 320){
      int g = idx / 160, c = idx - g * 160;
      float bv = 0.f;
      if (c < 150){
        int H = 3 * g + 2 + c / 50, o = c % 50;
        const float* cbp;
        switch (H){ case 2: cbp = c2; break; case 3: cbp = c3; break;
                    case 4: cbp = c4; break; case 5: cbp = c5; break;
                    case 6: cbp = c6; break; default: cbp = c7; break; }
        bv = cbp[o];
      }
      bias_p[idx] = bv;
    }
  } else if (blk < 3955){
    int idx = (blk - 3242) * 256 + tid;
    if (idx >= 1200 * 152) return;
    int row = idx / 152, col = idx - row * 152;
    wpad0[idx] = (col < 150) ? (_Float16)whh0[row * 150 + col] : (_Float16)0.f;
  } else if (blk < 4668){
    int idx = (blk - 3955) * 256 + tid;
    if (idx >= 1200 * 152) return;
    int row = idx / 152, col = idx - row * 152;
    wpad1[idx] = (col < 150) ? (_Float16)whh1[row * 150 + col] : (_Float16)0.f;
  } else if (blk < 6543){
    int idx = (blk - 4668) * 256 + tid;
    if (idx < 1600 * 300) ngram_u[idx] = 0u;
  } else if (blk < 6612){
    int idx = (blk - 6543) * 256 + tid;
    if (idx < NNODES) ecnt_u[idx] = 0u;
  } else {
    int idx = (blk - 6612) * 256 + tid;
    if (idx >= 16000 * 75) return;
    int row = idx / 75, q = idx - row * 75;
    const float4* t = (const float4*)tab;
    out1[idx] = t[x[row] * 75 + q];
  }
}

// ---------------- enc (fp16): enc[m][d] = tab[tok]+pos, pad rows zero -------
__global__ void gcnk_ench(const int* __restrict__ sx, const float* __restrict__ tab,
                          const float* __restrict__ pos, const int* __restrict__ sentlen,
                          _Float16* __restrict__ ench){
  int idx = blockIdx.x * 256 + threadIdx.x;
  if (idx >= MPAD * 75) return;
  int row = idx / 75, q = idx - row * 75;
  int d = q * 4;
  h4 o; o[0] = (_Float16)0.f; o[1] = (_Float16)0.f; o[2] = (_Float16)0.f; o[3] = (_Float16)0.f;
  if (row < MROWS){
    int n = row / 40, l = row - n * 40;
    int tok = sx[n * 40 + l];
    int p = (l < sentlen[n]) ? (l + 1) : 0;
    float4 a = *(const float4*)(tab + (size_t)tok * 300 + d);
    float4 b = *(const float4*)(pos + (size_t)p * 300 + d);
    o[0] = (_Float16)(a.x + b.x); o[1] = (_Float16)(a.y + b.y);
    o[2] = (_Float16)(a.z + b.z); o[3] = (_Float16)(a.w + b.w);
  }
  *(h4*)(ench + (size_t)row * 300 + d) = o;
}

// ---------------- fused conv GEMM via MFMA f16 — 2-phase double buffer ------
// BM=128, BN=160, BK=32. Two 18KB LDS buffers (A 8KB + B 10KB each) in the
// same 36KB footprint as the r7 kernel -> same 4 blocks/CU. Per chunk:
// issue next-chunk global_load_lds into buf^1, then ds_read+MFMA from buf,
// then ONE __syncthreads — its vmcnt(0) drain lands after the compute phase
// covered the prefetch latency (T3 minimum-2-phase recipe).
// 64B rows: store-side src slot (lane&3)^((lane>>3)&3); read-side byte
// (fq ^ ((row>>1)&3))<<4 — each v8h fragment read is a bijection onto the
// full 1KB subtile -> conflict-free.
__global__ __launch_bounds__(256)
void gcnk_convmfma(const _Float16* __restrict__ A, const _Float16* __restrict__ Bp,
                   const float* __restrict__ bias_p, unsigned int* __restrict__ ngram_u){
  __shared__ __align__(1024) char smem[36864];
  float* Cs = (float*)smem;                    // epilogue reuse: [128][33]
  const int tid = threadIdx.x;
  const int m0 = blockIdx.x * 128;
  const int grp = blockIdx.y;
  const char* Abase = (const char*)A;
  const char* Bbase = (const char*)(Bp + (size_t)grp * 160 * KSTRIDE);
  const int nch = (grp ? 2112 : 1216) >> 5;    // 66 / 38 chunks of K=32
  const int w = tid >> 6, lane = tid & 63;
  const int wm = (w >> 1) * 64, wn = (w & 1) * 80;
  const int fm = lane & 15, fq = lane >> 4;
  const int lrow = lane >> 2;                              // 0..15 (16 rows/issue)
  const int sslot = (((lane & 3) ^ ((lane >> 3) & 3)) << 4); // swizzled src byte in 64B row

  v4f acc[4][5] = {};

  auto stageChunk = [&](int buf, int kc){
    char* Asm = smem + buf * 18432;
    char* Bsm = Asm + 8192;
    // A: 8 issues of 1KB (16 rows x 64B); wave w does issues 2w, 2w+1
    #pragma unroll
    for (int ii = 0; ii < 2; ii++){
      int i = w * 2 + ii;
      const char* g = Abase + (size_t)(m0 + i * 16 + lrow) * 600 + kc * 2 + sslot;
      stage16(g, Asm + i * 1024, lane);
    }
    // B: 10 issues; wave w does j = w, w+4, w+8(<10)
    for (int j = w; j < 10; j += 4){
      const char* g = Bbase + (size_t)(j * 16 + lrow) * (KSTRIDE * 2) + kc * 2 + sslot;
      stage16(g, Bsm + j * 1024, lane);
    }
  };

  stageChunk(0, 0);
  __syncthreads();
  for (int c = 0; c < nch; c++){
    int cur = c & 1;
    if (c + 1 < nch) stageChunk(cur ^ 1, (c + 1) * 32);
    const char* Asm = smem + cur * 18432;
    const char* Bsm = Asm + 8192;
    v8h af[4], bf[5];
    #pragma unroll
    for (int mt = 0; mt < 4; mt++){
      int r = wm + mt * 16 + fm;
      af[mt] = *(const v8h*)(Asm + r * 64 + ((fq ^ ((r >> 1) & 3)) << 4));
    }
    #pragma unroll
    for (int nt = 0; nt < 5; nt++){
      int r = wn + nt * 16 + fm;
      bf[nt] = *(const v8h*)(Bsm + r * 64 + ((fq ^ ((r >> 1) & 3)) << 4));
    }
    #pragma unroll
    for (int mt = 0; mt < 4; mt++)
      #pragma unroll
      for (int nt = 0; nt < 5; nt++)
        acc[mt][nt] = __builtin_amdgcn_mfma_f32_16x16x32_f16(af[mt], bf[nt], acc[mt][nt], 0, 0, 0);
    __syncthreads();
  }

  // epilogue: 5 passes of 32 cols through LDS; relu+window-max -> atomicMax
  for (int p = 0; p < 5; p++){
    __syncthreads();
    #pragma unroll
    for (int nt = 0; nt < 5; nt++){
      int cstart = wn + nt * 16;
      if ((cstart >> 5) == p){
        int co = cstart - p * 32 + fm;
        #pragma unroll
        for (int mt = 0; mt < 4; mt++)
          #pragma unroll
          for (int r = 0; r < 4; r++)
            Cs[(wm + mt * 16 + fq * 4 + r) * 33 + co] = acc[mt][nt][r];
      }
    }
    __syncthreads();
    if (tid < 128){
      int cl = tid & 31, si = tid >> 5;        // 4 sentences can touch a 128-row tile
      int col = p * 32 + cl;                   // group-local col
      if (col < 150){
        int H = 3 * grp + 2 + col / 50, lh = 41 - H;
        int sent = m0 / 40 + si;
        if (sent < 1600){
          int rlo = sent * 40; if (rlo < m0) rlo = m0;
          int rhi = sent * 40 + lh; if (rhi > m0 + 128) rhi = m0 + 128;
          if (rlo < rhi){
            float bv = bias_p[grp * 160 + col];
            float vmax = 0.f;
            for (int r = rlo; r < rhi; r++){
              float v = Cs[(r - m0) * 33 + cl] + bv;
              vmax = fmaxf(vmax, v);
            }
            atomicMax(ngram_u + sent * 300 + grp * 150 + col, __float_as_uint(vmax));
          }
        }
      }
    }
  }
}

// ---------------- MFMA GEMM: C[M,N] = A[M,K](fp32->fp16) @ Wt[N,K]^T + b ----
// OUTH=1: write fp16 with row stride 160 (for the GCN aggregation gather).
template<int BM, int BN, int WMT, int WNT, int OUTH>
__global__ __launch_bounds__(256)
void gcnk_mgemm(const float* __restrict__ A, const float* __restrict__ Wt,
                const float* __restrict__ b1, const float* __restrict__ b2,
                void* __restrict__ Cv, int M, int N, int K){
  __shared__ __align__(16) _Float16 As[BM * 40];
  __shared__ __align__(16) _Float16 Bs[BN * 40];
  const int tid = threadIdx.x;
  const int m0 = blockIdx.x * BM, n0 = blockIdx.y * BN;
  const int w = tid >> 6, lane = tid & 63;
  const int wm = (w >> 1) * (WMT * 16), wn = (w & 1) * (WNT * 16);
  const int fm = lane & 15, fq = lane >> 4;
  v4f acc[WMT][WNT] = {};
  const int nch = (K + 31) >> 5;
  for (int ch = 0; ch < nch; ch++){
    int kc = ch * 32;
    #pragma unroll
    for (int j = 0; j < BM / 64; j++){      // A stage: BM rows x 32 halfs
      int u = tid + 256 * j;
      int row = u >> 2, cb = (u & 3) * 8;
      int gm = m0 + row, gk = kc + cb;
      v8h vv;
      if (gm < M && gk + 8 <= K){
        const float2* p = (const float2*)(A + (size_t)gm * K + gk);
        float2 q0 = p[0], q1 = p[1], q2 = p[2], q3 = p[3];
        vv[0] = (_Float16)q0.x; vv[1] = (_Float16)q0.y;
        vv[2] = (_Float16)q1.x; vv[3] = (_Float16)q1.y;
        vv[4] = (_Float16)q2.x; vv[5] = (_Float16)q2.y;
        vv[6] = (_Float16)q3.x; vv[7] = (_Float16)q3.y;
      } else {
        #pragma unroll
        for (int e = 0; e < 8; e++)
          vv[e] = (gm < M && gk + e < K) ? (_Float16)A[(size_t)gm * K + gk + e] : (_Float16)0.f;
      }
      *(v8h*)(As + row * 40 + cb) = vv;
    }
    {                                        // B stage: BN(=64) rows x 32 halfs
      int row = tid >> 2, cb = (tid & 3) * 8;
      int gn = n0 + row, gk = kc + cb;
      v8h vv;
      if (gn < N && gk + 8 <= K){
        const float2* p = (const float2*)(Wt + (size_t)gn * K + gk);
        float2 q0 = p[0], q1 = p[1], q2 = p[2], q3 = p[3];
        vv[0] = (_Float16)q0.x; vv[1] = (_Float16)q0.y;
        vv[2] = (_Float16)q1.x; vv[3] = (_Float16)q1.y;
        vv[4] = (_Float16)q2.x; vv[5] = (_Float16)q2.y;
        vv[6] = (_Float16)q3.x; vv[7] = (_Float16)q3.y;
      } else {
        #pragma unroll
        for (int e = 0; e < 8; e++)
          vv[e] = (gn < N && gk + e < K) ? (_Float16)Wt[(size_t)gn * K + gk + e] : (_Float16)0.f;
      }
      *(v8h*)(Bs + row * 40 + cb) = vv;
    }
    __syncthreads();
    v8h af[WMT], bf[WNT];
    #pragma unroll
    for (int mt = 0; mt < WMT; mt++)
      af[mt] = *(const v8h*)(As + (wm + mt * 16 + fm) * 40 + fq * 8);
    #pragma unroll
    for (int nt = 0; nt < WNT; nt++)
      bf[nt] = *(const v8h*)(Bs + (wn + nt * 16 + fm) * 40 + fq * 8);
    #pragma unroll
    for (int mt = 0; mt < WMT; mt++)
      #pragma unroll
      for (int nt = 0; nt < WNT; nt++)
        acc[mt][nt] = __builtin_amdgcn_mfma_f32_16x16x32_f16(af[mt], bf[nt], acc[mt][nt], 0, 0, 0);
    __syncthreads();
  }
  #pragma unroll
  for (int nt = 0; nt < WNT; nt++){
    int gn = n0 + wn + nt * 16 + fm;
    if (gn >= N) continue;
    float badd = (b1 ? b1[gn] : 0.f) + (b2 ? b2[gn] : 0.f);
    #pragma unroll
    for (int mt = 0; mt < WMT; mt++)
      #pragma unroll
      for (int r = 0; r < 4; r++){
        int gm = m0 + wm + mt * 16 + fq * 4 + r;
        if (gm < M){
          float val = acc[mt][nt][r] + badd;
          if (OUTH) ((_Float16*)Cv)[(size_t)gm * 160 + gn] = (_Float16)val;
          else      ((float*)Cv)[(size_t)gm * N + gn] = val;
        }
      }
  }
}

// ---------------- gc0 GEMM: A is fp16 [M][300] (pre-gathered node features) -
__global__ __launch_bounds__(256)
void gcnk_mgemmH(const _Float16* __restrict__ Ah, const float* __restrict__ Wt,
                 const float* __restrict__ b1, float* __restrict__ C, int M, int N){
  const int K = 300;
  __shared__ __align__(16) _Float16 As[128 * 40];
  __shared__ __align__(16) _Float16 Bs[64 * 40];
  const int tid = threadIdx.x;
  const int m0 = blockIdx.x * 128, n0 = blockIdx.y * 64;
  const int w = tid >> 6, lane = tid & 63;
  const int wm = (w >> 1) * 64, wn = (w & 1) * 32;
  const int fm = lane & 15, fq = lane >> 4;
  v4f acc[4][2] = {};
  for (int ch = 0; ch < 10; ch++){
    int kc = ch * 32;
    #pragma unroll
    for (int j = 0; j < 2; j++){            // A stage: 128 rows x 32 halfs
      int u = tid + 256 * j;
      int row = u >> 2, cb = (u & 3) * 8;
      int gm = m0 + row, gk = kc + cb;
      v8h vv;
      if (gm < M && gk + 8 <= K){
        const char* p = (const char*)(Ah + (size_t)gm * 300 + gk);
        union { uint2 u2[2]; v8h v; } t;
        t.u2[0] = *(const uint2*)p; t.u2[1] = *(const uint2*)(p + 8);
        vv = t.v;
      } else {
        #pragma unroll
        for (int e = 0; e < 8; e++)
          vv[e] = (gm < M && gk + e < K) ? Ah[(size_t)gm * 300 + gk + e] : (_Float16)0.f;
      }
      *(v8h*)(As + row * 40 + cb) = vv;
    }
    {                                        // B stage: 64 rows x 32 halfs (fp32 W)
      int row = tid >> 2, cb = (tid & 3) * 8;
      int gn = n0 + row, gk = kc + cb;
      v8h vv;
      if (gn < N && gk + 8 <= K){
        const float2* p = (const float2*)(Wt + (size_t)gn * K + gk);
        float2 q0 = p[0], q1 = p[1], q2 = p[2], q3 = p[3];
        vv[0] = (_Float16)q0.x; vv[1] = (_Float16)q0.y;
        vv[2] = (_Float16)q1.x; vv[3] = (_Float16)q1.y;
        vv[4] = (_Float16)q2.x; vv[5] = (_Float16)q2.y;
        vv[6] = (_Float16)q3.x; vv[7] = (_Float16)q3.y;
      } else {
        #pragma unroll
        for (int e = 0; e < 8; e++)
          vv[e] = (gn < N && gk + e < K) ? (_Float16)Wt[(size_t)gn * K + gk + e] : (_Float16)0.f;
      }
      *(v8h*)(Bs + row * 40 + cb) = vv;
    }
    __syncthreads();
    v8h af[4], bf[2];
    #pragma unroll
    for (int mt = 0; mt < 4; mt++)
      af[mt] = *(const v8h*)(As + (wm + mt * 16 + fm) * 40 + fq * 8);
    #pragma unroll
    for (int nt = 0; nt < 2; nt++)
      bf[nt] = *(const v8h*)(Bs + (wn + nt * 16 + fm) * 40 + fq * 8);
    #pragma unroll
    for (int mt = 0; mt < 4; mt++)
      #pragma unroll
      for (int nt = 0; nt < 2; nt++)
        acc[mt][nt] = __builtin_amdgcn_mfma_f32_16x16x32_f16(af[mt], bf[nt], acc[mt][nt], 0, 0, 0);
    __syncthreads();
  }
  #pragma unroll
  for (int nt = 0; nt < 2; nt++){
    int gn = n0 + wn + nt * 16 + fm;
    if (gn >= N) continue;
    float badd = b1[gn];
    #pragma unroll
    for (int mt = 0; mt < 4; mt++)
      #pragma unroll
      for (int r = 0; r < 4; r++){
        int gm = m0 + wm + mt * 16 + fq * 4 + r;
        if (gm < M) C[(size_t)gm * N + gn] = acc[mt][nt][r] + badd;
      }
  }
}

// ---------------- flexible small GEMM with fused gather/concat/mask/pos -----
__global__ __launch_bounds__(256)
void gcnk_mgemmF(const float* __restrict__ A1, const int* __restrict__ mapA,
                 const float* __restrict__ A2, const int* __restrict__ mapB,
                 const int* __restrict__ glen, int usemask,
                 const float* __restrict__ apos,
                 const float* __restrict__ Wt, const float* __restrict__ b1,
                 const float* __restrict__ b2, float* __restrict__ C,
                 int M, int N, int K){
  const int BM = 64, WMT = 2, WNT = 2;
  __shared__ __align__(16) _Float16 As[BM * 40];
  __shared__ __align__(16) _Float16 Bs[64 * 40];
  const int tid = threadIdx.x;
  const int m0 = blockIdx.x * BM, n0 = blockIdx.y * 64;
  const int w = tid >> 6, lane = tid & 63;
  const int wm = (w >> 1) * (WMT * 16), wn = (w & 1) * (WNT * 16);
  const int fm = lane & 15, fq = lane >> 4;
  v4f acc[WMT][WNT] = {};
  const int nch = (K + 31) >> 5;
  for (int ch = 0; ch < nch; ch++){
    int kc = ch * 32;
    {                                        // A stage: 64 rows x 32 halfs
      int row = tid >> 2, cb = (tid & 3) * 8;
      int gm = m0 + row, gk = kc + cb;
      v8h vv;
      bool ok = (gm < M);
      if (ok && usemask){
        int b = gm / 50;
        if (gm - b * 50 >= glen[b]) ok = false;
      }
      if (!ok){
        #pragma unroll
        for (int e = 0; e < 8; e++) vv[e] = (_Float16)0.f;
      } else if (!A2){
        int r = mapA ? mapA[gm] : gm;
        const float* base = A1 + (size_t)r * K;
        if (gk + 8 <= K){
          const float2* p = (const float2*)(base + gk);
          float2 q0 = p[0], q1 = p[1], q2 = p[2], q3 = p[3];
          if (apos){
            const float2* a2 = (const float2*)(apos + (size_t)(gm % 50) * K + gk);
            float2 r0 = a2[0], r1 = a2[1], r2 = a2[2], r3 = a2[3];
            q0.x += r0.x; q0.y += r0.y; q1.x += r1.x; q1.y += r1.y;
            q2.x += r2.x; q2.y += r2.y; q3.x += r3.x; q3.y += r3.y;
          }
          vv[0] = (_Float16)q0.x; vv[1] = (_Float16)q0.y;
          vv[2] = (_Float16)q1.x; vv[3] = (_Float16)q1.y;
          vv[4] = (_Float16)q2.x; vv[5] = (_Float16)q2.y;
          vv[6] = (_Float16)q3.x; vv[7] = (_Float16)q3.y;
        } else {
          #pragma unroll
          for (int e = 0; e < 8; e++){
            int c = gk + e;
            float vf = (c < K) ? base[c] : 0.f;
            if (apos && c < K) vf += apos[(size_t)(gm % 50) * K + c];
            vv[e] = (_Float16)vf;
          }
        }
      } else {
        int rA = mapA ? mapA[gm] : gm;
        int rB = mapB ? mapB[gm] : gm;
        const float* pa = A1 + (size_t)rA * 150;
        const float* pb = A2 + (size_t)rB * 150;
        if (gk + 8 <= 150){
          const float2* p = (const float2*)(pa + gk);
          float2 q0 = p[0], q1 = p[1], q2 = p[2], q3 = p[3];
          vv[0] = (_Float16)q0.x; vv[1] = (_Float16)q0.y;
          vv[2] = (_Float16)q1.x; vv[3] = (_Float16)q1.y;
          vv[4] = (_Float16)q2.x; vv[5] = (_Float16)q2.y;
          vv[6] = (_Float16)q3.x; vv[7] = (_Float16)q3.y;
        } else if (gk >= 152 && gk + 8 <= K){
          const float2* p = (const float2*)(pb + gk - 150);
          float2 q0 = p[0], q1 = p[1], q2 = p[2], q3 = p[3];
          vv[0] = (_Float16)q0.x; vv[1] = (_Float16)q0.y;
          vv[2] = (_Float16)q1.x; vv[3] = (_Float16)q1.y;
          vv[4] = (_Float16)q2.x; vv[5] = (_Float16)q2.y;
          vv[6] = (_Float16)q3.x; vv[7] = (_Float16)q3.y;
        } else {
          #pragma unroll
          for (int e = 0; e < 8; e++){
            int c = gk + e;
            vv[e] = (c < 150) ? (_Float16)pa[c]
                  : ((c < K) ? (_Float16)pb[c - 150] : (_Float16)0.f);
          }
        }
      }
      *(v8h*)(As + row * 40 + cb) = vv;
    }
    {                                        // B stage: 64 rows x 32 halfs
      int row = tid >> 2, cb = (tid & 3) * 8;
      int gn = n0 + row, gk = kc + cb;
      v8h vv;
      if (gn < N && gk + 8 <= K){
        const float2* p = (const float2*)(Wt + (size_t)gn * K + gk);
        float2 q0 = p[0], q1 = p[1], q2 = p[2], q3 = p[3];
        vv[0] = (_Float16)q0.x; vv[1] = (_Float16)q0.y;
        vv[2] = (_Float16)q1.x; vv[3] = (_Float16)q1.y;
        vv[4] = (_Float16)q2.x; vv[5] = (_Float16)q2.y;
        vv[6] = (_Float16)q3.x; vv[7] = (_Float16)q3.y;
      } else {
        #pragma unroll
        for (int e = 0; e < 8; e++)
          vv[e] = (gn < N && gk + e < K) ? (_Float16)Wt[(size_t)gn * K + gk + e] : (_Float16)0.f;
      }
      *(v8h*)(Bs + row * 40 + cb) = vv;
    }
    __syncthreads();
    v8h af[WMT], bf[WNT];
    #pragma unroll
    for (int mt = 0; mt < WMT; mt++)
      af[mt] = *(const v8h*)(As + (wm + mt * 16 + fm) * 40 + fq * 8);
    #pragma unroll
    for (int nt = 0; nt < WNT; nt++)
      bf[nt] = *(const v8h*)(Bs + (wn + nt * 16 + fm) * 40 + fq * 8);
    #pragma unroll
    for (int mt = 0; mt < WMT; mt++)
      #pragma unroll
      for (int nt = 0; nt < WNT; nt++)
        acc[mt][nt] = __builtin_amdgcn_mfma_f32_16x16x32_f16(af[mt], bf[nt], acc[mt][nt], 0, 0, 0);
    __syncthreads();
  }
  #pragma unroll
  for (int nt = 0; nt < WNT; nt++){
    int gn = n0 + wn + nt * 16 + fm;
    if (gn >= N) continue;
    float badd = (b1 ? b1[gn] : 0.f) + (b2 ? b2[gn] : 0.f);
    #pragma unroll
    for (int mt = 0; mt < WMT; mt++)
      #pragma unroll
      for (int r = 0; r < 4; r++){
        int gm = m0 + wm + mt * 16 + fq * 4 + r;
        if (gm < M) C[(size_t)gm * N + gn] = acc[mt][nt][r] + badd;
      }
  }
}

// ---------------- paired variant: blockIdx.z selects one of two param sets --
struct FArgs {
  const float* A1; const int* mapA;
  const float* A2; const int* mapB;
  const float* Wt; const float* b1; const float* b2;
  float* C;
};

__global__ __launch_bounds__(256)
void gcnk_mgemmF2(FArgs pa, FArgs pb, int M, int N, int K){
  const int BM = 64, WMT = 2, WNT = 2;
  __shared__ __align__(16) _Float16 As[BM * 40];
  __shared__ __align__(16) _Float16 Bs[64 * 40];
  const FArgs P = blockIdx.z ? pb : pa;
  const int tid = threadIdx.x;
  const int m0 = blockIdx.x * BM, n0 = blockIdx.y * 64;
  const int w = tid >> 6, lane = tid & 63;
  const int wm = (w >> 1) * (WMT * 16), wn = (w & 1) * (WNT * 16);
  const int fm = lane & 15, fq = lane >> 4;
  v4f acc[WMT][WNT] = {};
  const int nch = (K + 31) >> 5;
  for (int ch = 0; ch < nch; ch++){
    int kc = ch * 32;
    {                                        // A stage: 64 rows x 32 halfs
      int row = tid >> 2, cb = (tid & 3) * 8;
      int gm = m0 + row, gk = kc + cb;
      v8h vv;
      if (gm >= M){
        #pragma unroll
        for (int e = 0; e < 8; e++) vv[e] = (_Float16)0.f;
      } else if (!P.A2){
        int r = P.mapA ? P.mapA[gm] : gm;
        const float* base = P.A1 + (size_t)r * K;
        if (gk + 8 <= K){
          const float2* p = (const float2*)(base + gk);
          float2 q0 = p[0], q1 = p[1], q2 = p[2], q3 = p[3];
          vv[0] = (_Float16)q0.x; vv[1] = (_Float16)q0.y;
          vv[2] = (_Float16)q1.x; vv[3] = (_Float16)q1.y;
          vv[4] = (_Float16)q2.x; vv[5] = (_Float16)q2.y;
          vv[6] = (_Float16)q3.x; vv[7] = (_Float16)q3.y;
        } else {
          #pragma unroll
          for (int e = 0; e < 8; e++)
            vv[e] = (gk + e < K) ? (_Float16)base[gk + e] : (_Float16)0.f;
        }
      } else {
        int rA = P.mapA ? P.mapA[gm] : gm;
        int rB = P.mapB ? P.mapB[gm] : gm;
        const float* paa = P.A1 + (size_t)rA * 150;
        const float* pbb = P.A2 + (size_t)rB * 150;
        if (gk + 8 <= 150){
          const float2* p = (const float2*)(paa + gk);
          float2 q0 = p[0], q1 = p[1], q2 = p[2], q3 = p[3];
          vv[0] = (_Float16)q0.x; vv[1] = (_Float16)q0.y;
          vv[2] = (_Float16)q1.x; vv[3] = (_Float16)q1.y;
          vv[4] = (_Float16)q2.x; vv[5] = (_Float16)q2.y;
          vv[6] = (_Float16)q3.x; vv[7] = (_Float16)q3.y;
        } else if (gk >= 152 && gk + 8 <= K){
          const float2* p = (const float2*)(pbb + gk - 150);
          float2 q0 = p[0], q1 = p[1], q2 = p[2], q3 = p[3];
          vv[0] = (_Float16)q0.x; vv[1] = (_Float16)q0.y;
          vv[2] = (_Float16)q1.x; vv[3] = (_Float16)q1.y;
          vv[4] = (_Float16)q2.x; vv[5] = (_Float16)q2.y;
          vv[6] = (_Float16)q3.x; vv[7] = (_Float16)q3.y;
        } else {
          #pragma unroll
          for (int e = 0; e < 8; e++){
            int c = gk + e;
            vv[e] = (c < 150) ? (_Float16)paa[c]
                  : ((c < K) ? (_Float16)pbb[c - 150] : (_Float16)0.f);
          }
        }
      }
      *(v8h*)(As + row * 40 + cb) = vv;
    }
    {                                        // B stage: 64 rows x 32 halfs
      int row = tid >> 2, cb = (tid & 3) * 8;
      int gn = n0 + row, gk = kc + cb;
      v8h vv;
      if (gn < N && gk + 8 <= K){
        const float2* p = (const float2*)(P.Wt + (size_t)gn * K + gk);
        float2 q0 = p[0], q1 = p[1], q2 = p[2], q3 = p[3];
        vv[0] = (_Float16)q0.x; vv[1] = (_Float16)q0.y;
        vv[2] = (_Float16)q1.x; vv[3] = (_Float16)q1.y;
        vv[4] = (_Float16)q2.x; vv[5] = (_Float16)q2.y;
        vv[6] = (_Float16)q3.x; vv[7] = (_Float16)q3.y;
      } else {
        #pragma unroll
        for (int e = 0; e < 8; e++)
          vv[e] = (gn < N && gk + e < K) ? (_Float16)P.Wt[(size_t)gn * K + gk + e] : (_Float16)0.f;
      }
      *(v8h*)(Bs + row * 40 + cb) = vv;
    }
    __syncthreads();
    v8h af[WMT], bf[WNT];
    #pragma unroll
    for (int mt = 0; mt < WMT; mt++)
      af[mt] = *(const v8h*)(As + (wm + mt * 16 + fm) * 40 + fq * 8);
    #pragma unroll
    for (int nt = 0; nt < WNT; nt++)
      bf[nt] = *(const v8h*)(Bs + (wn + nt * 16 + fm) * 40 + fq * 8);
    #pragma unroll
    for (int mt = 0; mt < WMT; mt++)
      #pragma unroll
      for (int nt = 0; nt < WNT; nt++)
        acc[mt][nt] = __builtin_amdgcn_mfma_f32_16x16x32_f16(af[mt], bf[nt], acc[mt][nt], 0, 0, 0);
    __syncthreads();
  }
  #pragma unroll
  for (int nt = 0; nt < WNT; nt++){
    int gn = n0 + wn + nt * 16 + fm;
    if (gn >= N) continue;
    float badd = (P.b1 ? P.b1[gn] : 0.f) + (P.b2 ? P.b2[gn] : 0.f);
    #pragma unroll
    for (int mt = 0; mt < WMT; mt++)
      #pragma unroll
      for (int r = 0; r < 4; r++){
        int gm = m0 + wm + mt * 16 + fq * 4 + r;
        if (gm < M) P.C[(size_t)gm * N + gn] = acc[mt][nt][r] + badd;
      }
  }
}

// ---------------- node feature assembly, fp16 out [17600 x 300] -------------
__global__ void gcnk_nodes_in_h(const int* __restrict__ x, const float* __restrict__ tab,
                                const float* __restrict__ cnnf, const float* __restrict__ lstmf,
                                h2* __restrict__ out){
  int idx = blockIdx.x * 256 + threadIdx.x;
  if (idx >= NNODES * 150) return;
  int nrow = idx / 150, q = idx - nrow * 150;
  int d = q * 2;
  int b = nrow / 550, j = nrow - b * 550;
  float2 v;
  if (j < 500) v = *(const float2*)(tab + (size_t)x[b * 500 + j] * 300 + d);
  else {
    int r = b * 50 + (j - 500);
    if (d < 150) v = *(const float2*)(cnnf + (size_t)r * 150 + d);
    else         v = *(const float2*)(lstmf + (size_t)r * 150 + d - 150);
  }
  h2 o; o[0] = (_Float16)v.x; o[1] = (_Float16)v.y;
  out[idx] = o;
}

// ---------------- LSTM recurrence: weights in VGPRs, h fp16 in LDS ----------
__global__ __launch_bounds__(640)
void gcnk_lstm(const float* __restrict__ xf, const float* __restrict__ xr,
               const _Float16* __restrict__ wpad, float* __restrict__ fo,
               float* __restrict__ ro){
  int b = blockIdx.x >> 1, dir = blockIdx.x & 1;
  const float* xih = dir ? xr : xf;
  float* out = dir ? ro : fo;
  __shared__ __align__(16) _Float16 hh[160];
  __shared__ float gates[600];
  const int tid = threadIdx.x;

  h2 w[76];
  if (tid < 600){
    const h2* wrow = (const h2*)(wpad + ((size_t)dir * 600 + tid) * 152);
    #pragma unroll
    for (int j = 0; j < 76; j++) w[j] = wrow[j];
  }
  for (int u = tid; u < 160; u += 640) hh[u] = (_Float16)0.f;
  float creg = 0.f;
  __syncthreads();

  for (int t = 0; t < 50; t++){
    if (tid < 600){
      float acc = xih[(b * 50 + t) * 600 + tid];
      float a0 = 0.f, a1 = 0.f, a2 = 0.f, a3 = 0.f;   // break the dep chain 4-way
      #pragma unroll
      for (int j = 0; j < 19; j++){
        union { float4 f; h2 h[4]; } u;
        u.f = *(const float4*)(hh + j * 8);
        a0 = fdot2_(w[4 * j + 0], u.h[0], a0);
        a1 = fdot2_(w[4 * j + 1], u.h[1], a1);
        a2 = fdot2_(w[4 * j + 2], u.h[2], a2);
        a3 = fdot2_(w[4 * j + 3], u.h[3], a3);
      }
      gates[tid] = acc + ((a0 + a1) + (a2 + a3));
    }
    __syncthreads();
    if (tid < 150){
      float ig = sigm(gates[tid]);
      float fg = sigm(gates[150 + tid]);
      float gg = tanhf(gates[300 + tid]);
      float og = sigm(gates[450 + tid]);
      creg = fg * creg + ig * gg;
      float hn = og * tanhf(creg);
      hh[tid] = (_Float16)hn;
      out[(b * 50 + t) * 150 + tid] = hn;
    }
    __syncthreads();
  }
}

// ---------------- GCN: CSR build (counting sort by dst) ---------------------
__global__ void gcnk_hist(const int* __restrict__ ei, int* __restrict__ ecnt){
  int e = blockIdx.x * 256 + threadIdx.x;
  if (e < EDGES) atomicAdd(&ecnt[ei[EDGES + e]], 1);
}

// fast single-block scan: serial 18/thread + wave shfl scan + 16-entry scan
// also emits dis[i] = rsqrt(deg+1) (fused dis2)
__global__ __launch_bounds__(1024)
void gcnk_scan(const int* __restrict__ ecnt, int* __restrict__ eoff,
               int* __restrict__ ecur, float* __restrict__ dis){
  __shared__ int wsum[16];
  int tid = threadIdx.x;
  int base = tid * 18;
  int pre[18];
  int s = 0;
  #pragma unroll
  for (int i = 0; i < 18; i++){
    int idx = base + i;
    int c = (idx < NNODES) ? ecnt[idx] : 0;
    if (idx < NNODES) dis[idx] = rsqrtf((float)(c + 1));
    pre[i] = s; s += c;
  }
  int lane = tid & 63, wid = tid >> 6;
  int run = s;
  #pragma unroll
  for (int off = 1; off < 64; off <<= 1){
    int y = __shfl_up(run, off, 64);
    if (lane >= off) run += y;
  }
  if (lane == 63) wsum[wid] = run;
  __syncthreads();
  if (tid == 0){
    int a = 0;
    #pragma unroll
    for (int i = 0; i < 16; i++){ int t2 = wsum[i]; wsum[i] = a; a += t2; }
  }
  __syncthreads();
  int excl = wsum[wid] + run - s;
  #pragma unroll
  for (int i = 0; i < 18; i++){
    int idx = base + i;
    if (idx < NNODES){
      int e = excl + pre[i];
      eoff[idx] = e; ecur[idx] = e;
    }
  }
}

__global__ void gcnk_scatter(const int* __restrict__ ei, int* __restrict__ ecur,
                             int* __restrict__ esrc){
  int e = blockIdx.x * 256 + threadIdx.x;
  if (e < EDGES){
    int d = ei[EDGES + e];
    int p = atomicAdd(&ecur[d], 1);
    esrc[p] = ei[e];
  }
}

// ---------------- GCN aggregation: fp16 gather + fused bias/elu epilogue ----
__global__ __launch_bounds__(128)
void gcnk_aggcsr_h(const int* __restrict__ eoff, const int* __restrict__ ecnt,
                   const int* __restrict__ esrc, const float* __restrict__ dis,
                   const _Float16* __restrict__ xw, const float* __restrict__ bias,
                   float* __restrict__ out, int doelu){
  int d = blockIdx.x, t = threadIdx.x;
  float dd = dis[d];
  bool act = t < 75;
  float ax0 = 0.f, ay0 = 0.f, ax1 = 0.f, ay1 = 0.f;
  if (act){
    h2 v = *(const h2*)(xw + (size_t)d * 160 + 2 * t);
    ax0 = (float)v[0] * dd; ay0 = (float)v[1] * dd;
  }
  int beg = eoff[d], end = beg + ecnt[d];
  int j = beg;
  for (; j + 1 < end; j += 2){
    int s0 = esrc[j], s1 = esrc[j + 1];
    float d0 = dis[s0], d1 = dis[s1];
    if (act){
      h2 v0 = *(const h2*)(xw + (size_t)s0 * 160 + 2 * t);
      h2 v1 = *(const h2*)(xw + (size_t)s1 * 160 + 2 * t);
      ax0 += (float)v0[0] * d0; ay0 += (float)v0[1] * d0;
      ax1 += (float)v1[0] * d1; ay1 += (float)v1[1] * d1;
    }
  }
  if (j < end){
    int s = esrc[j];
    float ds_ = dis[s];
    if (act){
      h2 v = *(const h2*)(xw + (size_t)s * 160 + 2 * t);
      ax0 += (float)v[0] * ds_; ay0 += (float)v[1] * ds_;
    }
  }
  if (act){
    float o0 = (ax0 + ax1) * dd + bias[2 * t];
    float o1 = (ay0 + ay1) * dd + bias[2 * t + 1];
    if (doelu){
      o0 = (o0 > 0.f) ? o0 : expm1f(o0);
      o1 = (o1 > 0.f) ? o1 : expm1f(o1);
    }
    *(float2*)(out + (size_t)d * 150 + 2 * t) = make_float2(o0, o1);
  }
}

// ============================================================================
extern "C" void kernel_launch(void* const* d_in, const int* in_sizes, int n_in,
                              void* d_out, int out_size, void* d_ws, size_t ws_size,
                              hipStream_t stream){
  (void)in_sizes; (void)n_in; (void)out_size; (void)ws_size;

  char* wsb = (char*)d_ws;
  size_t off = 0;
  auto alloc = [&](size_t bytes) -> void* {
    void* p = wsb + off;
    off = (off + bytes + 255) & ~(size_t)255;
    return p;
  };
  float* pos_tab  = (float*)alloc(513 * 300 * 4);
  int*   sentlen  = (int*)alloc(1600 * 4);
  int*   glen     = (int*)alloc(32 * 4);
  int*   rowmap   = (int*)alloc(1600 * 4);
  float* ngram    = (float*)alloc(1600 * 300 * 4);
  float* cnn_feat = (float*)alloc(1600 * 150 * 4);
  float* xih_f    = (float*)alloc(1600 * 600 * 4);
  float* xih_r    = (float*)alloc(1600 * 600 * 4);
  float* f0       = (float*)alloc(1600 * 150 * 4);
  float* r0       = (float*)alloc(1600 * 150 * 4);
  float* f1       = (float*)alloc(1600 * 150 * 4);
  float* r1       = (float*)alloc(1600 * 150 * 4);
  float* lstm_ft  = (float*)alloc(1600 * 150 * 4);
  h2*    nodes_ih = (h2*)alloc((size_t)NNODES * 150 * 4);   // fp16 [NNODES][300]
  float* nodes    = (float*)alloc((size_t)NNODES * 150 * 4);
  float* dis      = (float*)alloc(NNODES * 4);
  _Float16* xwh   = (_Float16*)alloc((size_t)NNODES * 160 * 2);
  _Float16* ench  = (_Float16*)alloc((size_t)MPAD * 300 * 2);
  _Float16* Bp    = (_Float16*)alloc((size_t)2 * 160 * KSTRIDE * 2);
  float* bias_p   = (float*)alloc(320 * 4);
  _Float16* wpad0 = (_Float16*)alloc(1200 * 152 * 2);
  _Float16* wpad1 = (_Float16*)alloc(1200 * 152 * 2);
  int*   ecnt     = (int*)alloc(NNODES * 4);
  int*   eoff     = (int*)alloc(NNODES * 4);
  int*   ecur     = (int*)alloc(NNODES * 4);
  int*   esrc     = (int*)alloc(EDGES * 4);

  const int*   x   = (const int*)d_in[0];
  const int*   sx  = (const int*)d_in[1];
  const int*   ei  = (const int*)d_in[2];
  const float* tab = (const float*)d_in[3];
  const float *cw[6], *cb[6];
  for (int h = 0; h < 6; h++){ cw[h] = (const float*)d_in[4 + 2 * h]; cb[h] = (const float*)d_in[5 + 2 * h]; }
  const float* cnnw = (const float*)d_in[16]; const float* cnnb = (const float*)d_in[17];
  const float* wih0 = (const float*)d_in[18]; const float* whh0 = (const float*)d_in[19];
  const float* bih0 = (const float*)d_in[20]; const float* bhh0 = (const float*)d_in[21];
  const float* wih1 = (const float*)d_in[22]; const float* whh1 = (const float*)d_in[23];
  const float* bih1 = (const float*)d_in[24]; const float* bhh1 = (const float*)d_in[25];
  const float* lpw  = (const float*)d_in[26]; const float* lpb  = (const float*)d_in[27];
  const float* g0w  = (const float*)d_in[28]; const float* g0b  = (const float*)d_in[29];
  const float* g1w  = (const float*)d_in[30]; const float* g1b  = (const float*)d_in[31];
  const float* g2w  = (const float*)d_in[32]; const float* g2b  = (const float*)d_in[33];

  float* out0 = (float*)d_out;
  float4* out1 = (float4*)((float*)d_out + OUT0SZ);

  auto mgemmLH = [&](const float* A, const float* W, void* C, int M, int N, int K){
    dim3 g((M + 127) / 128, (N + 63) / 64);
    gcnk_mgemm<128, 64, 4, 2, 1><<<g, 256, 0, stream>>>(A, W, nullptr, nullptr, C, M, N, K);
  };
  // flexible small GEMM (M=1600)
  auto mgemmF = [&](const float* A1, const int* mapA, const float* A2, const int* mapB,
                    const int* gl, int um, const float* apos, const float* W,
                    const float* b1, const float* b2, float* C, int N, int K){
    dim3 g(25, (N + 63) / 64);
    gcnk_mgemmF<<<g, 256, 0, stream>>>(A1, mapA, A2, mapB, gl, um, apos, W, b1, b2, C, 1600, N, K);
  };

  // ---- pipeline ----
  gcnk_prep2<<<1, 1024, 0, stream>>>(sx, sentlen, glen, rowmap);
  gcnk_mergedprep<<<11300, 256, 0, stream>>>(
      pos_tab, cw[0], cw[1], cw[2], cw[3], cw[4], cw[5],
      cb[0], cb[1], cb[2], cb[3], cb[4], cb[5], Bp, bias_p,
      whh0, wpad0, whh1, wpad1, (unsigned int*)ngram, (unsigned int*)ecnt,
      x, tab, out1);
  gcnk_ench<<<(MPAD * 75 + 255) / 256, 256, 0, stream>>>(sx, tab, pos_tab, sentlen, ench);

  // conv: 2-phase double-buffered (BK=32), grid (500,2)
  {
    dim3 g(500, 2);
    gcnk_convmfma<<<g, 256, 0, stream>>>(ench, Bp, bias_p, (unsigned int*)ngram);
  }

  // cnn_proj with POS-add fused into A-stage
  mgemmF(ngram, nullptr, nullptr, nullptr, nullptr, 0, pos_tab,
         cnnw, cnnb, nullptr, cnn_feat, 150, 300);

  // BiLSTM layer 0: fwd+rev xih in ONE z=2 launch (permute fused into A-load)
  {
    FArgs pa{cnn_feat, nullptr, nullptr, nullptr, wih0,             bih0,       bhh0,       xih_f};
    FArgs pb{cnn_feat, rowmap,  nullptr, nullptr, wih0 + 600 * 150, bih0 + 600, bhh0 + 600, xih_r};
    dim3 g(25, 10, 2);
    gcnk_mgemmF2<<<g, 256, 0, stream>>>(pa, pb, 1600, 600, 150);
  }
  gcnk_lstm<<<64, 640, 0, stream>>>(xih_f, xih_r, wpad0, f0, r0);

  // BiLSTM layer 1: fwd+rev xih in ONE z=2 launch (concat fused into A-load)
  {
    FArgs pa{f0, nullptr, r0, rowmap,  wih1,             bih1,       bhh1,       xih_f};
    FArgs pb{f0, rowmap,  r0, nullptr, wih1 + 600 * 300, bih1 + 600, bhh1 + 600, xih_r};
    dim3 g(25, 10, 2);
    gcnk_mgemmF2<<<g, 256, 0, stream>>>(pa, pb, 1600, 600, 300);
  }
  gcnk_lstm<<<64, 640, 0, stream>>>(xih_f, xih_r, wpad1, f1, r1);

  // masked projection (concat + mask fused into A-load)
  mgemmF(f1, nullptr, r1, rowmap, glen, 1, nullptr, lpw, lpb, nullptr, lstm_ft, 150, 300);

  // node features (fp16, gathered once) + gc0 (fp16-A GEMM)
  gcnk_nodes_in_h<<<(NNODES * 150 + 255) / 256, 256, 0, stream>>>(x, tab, cnn_feat, lstm_ft, nodes_ih);
  {
    dim3 g(138, 3);
    gcnk_mgemmH<<<g, 256, 0, stream>>>((const _Float16*)nodes_ih, g0w, g0b, nodes, NNODES, 150);
  }

  // CSR build (once, reused by both GCN layers); dis fused into scan
  gcnk_hist<<<2200, 256, 0, stream>>>(ei, ecnt);
  gcnk_scan<<<1, 1024, 0, stream>>>(ecnt, eoff, ecur, dis);
  gcnk_scatter<<<2200, 256, 0, stream>>>(ei, ecur, esrc);

  // gc1 + elu (fp16 xw gather, fused bias+elu epilogue)
  mgemmLH(nodes, g1w, xwh, NNODES, 150, 150);
  gcnk_aggcsr_h<<<NNODES, 128, 0, stream>>>(eoff, ecnt, esrc, dis, xwh, g1b, nodes, 1);

  // gc2 -> output 0 (fused bias epilogue)
  mgemmLH(nodes, g2w, xwh, NNODES, 150, 150);
  gcnk_aggcsr_h<<<NNODES, 128, 0, stream>>>(eoff, ecnt, esrc, dis, xwh, g2b, out0, 0);
}

// Round 12
// 756.374 us; speedup vs baseline: 1.0240x; 1.0240x over previous
//
#include <hip/hip_runtime.h>
#include <stdint.h>
#include <math.h>

// Problem constants (match reference)
#define EDGES 563200
#define NNODES 17600    // B*(NW+NS)
#define OUT0SZ 2640000  // 17600*150
#define MROWS 64000     // 1600 sentences * 40 positions
#define MPAD  64016     // + zero pad rows for window overhang
#define KSTRIDE 2112    // B pack row stride (halfs)

typedef _Float16 h2 __attribute__((ext_vector_type(2)));
typedef _Float16 h4 __attribute__((ext_vector_type(4)));
typedef _Float16 v8h __attribute__((ext_vector_type(8)));
typedef float v4f __attribute__((ext_vector_type(4)));

__device__ __forceinline__ float sigm(float x){ return 1.f / (1.f + expf(-x)); }

__device__ __forceinline__ float fdot2_(h2 a, h2 b, float c){
#if __has_builtin(__builtin_amdgcn_fdot2)
  return __builtin_amdgcn_fdot2(a, b, c, false);
#else
  return c + (float)a.x * (float)b.x + (float)a.y * (float)b.y;
#endif
}

// async global->LDS, 16B per lane; dest = wave-uniform base + lane*16
__device__ __forceinline__ void stage16(const char* g, char* lds_base, int lane){
#if __has_builtin(__builtin_amdgcn_global_load_lds)
  __builtin_amdgcn_global_load_lds(
      (const __attribute__((address_space(1))) void*)g,
      (__attribute__((address_space(3))) void*)lds_base, 16, 0, 0);
#else
  uint4 v = *(const uint4*)g;
  *(uint4*)(lds_base + lane * 16) = v;
#endif
}

// ---------------- sentlen + glen + rowmap, one block ------------------------
__global__ __launch_bounds__(1024)
void gcnk_prep2(const int* __restrict__ sx, int* __restrict__ sentlen,
                int* __restrict__ glen_g, int* __restrict__ rowmap){
  __shared__ int sg[32];
  int tid = threadIdx.x;
  for (int i = tid; i < 1600; i += 1024){
    int c = 0;
    for (int j = 0; j < 40; j++) c += (sx[i * 40 + j] != 0);
    sentlen[i] = c;
  }
  if (tid < 32){
    int c = 0;
    for (int s = 0; s < 50; s++) c += (sx[tid * 2000 + s * 40] != 0);
    glen_g[tid] = c; sg[tid] = c;
  }
  __syncthreads();
  for (int i = tid; i < 1600; i += 1024){
    int b = i / 50, t = i - b * 50, g = sg[b];
    rowmap[i] = b * 50 + ((t < g) ? (g - 1 - t) : t);
  }
}

// ---------------- merged prep: postab | bpack | whhpack x2 | zero x2 | embw -
__global__ __launch_bounds__(256)
void gcnk_mergedprep(float* __restrict__ pos,
                     const float* w2, const float* w3, const float* w4,
                     const float* w5, const float* w6, const float* w7,
                     const float* c2, const float* c3, const float* c4,
                     const float* c5, const float* c6, const float* c7,
                     _Float16* __restrict__ Bp, float* __restrict__ bias_p,
                     const float* __restrict__ whh0, _Float16* __restrict__ wpad0,
                     const float* __restrict__ whh1, _Float16* __restrict__ wpad1,
                     unsigned int* __restrict__ ngram_u, unsigned int* __restrict__ ecnt_u,
                     const int* __restrict__ x, const float* __restrict__ tab,
                     float4* __restrict__ out1){
  int blk = blockIdx.x, tid = threadIdx.x;
  if (blk < 602){
    int idx = blk * 256 + tid;
    if (idx >= 513 * 300) return;
    int p = idx / 300, i = idx - p * 300;
    float v = 0.f;
    if (p != 0){
      double expo = (double)(2 * (i / 2)) / 300.0;
      double ang = (double)p / pow(10000.0, expo);
      v = (float)((i & 1) ? cos(ang) : sin(ang));
    }
    pos[idx] = v;
  } else if (blk < 3242){
    int idx = (blk - 602) * 256 + tid;
    if (idx < 2 * 160 * KSTRIDE){
      int n = idx / KSTRIDE, kk = idx - n * KSTRIDE;
      int g = n / 160, c = n - g * 160;
      _Float16 v = (_Float16)0.f;
      if (c < 150){
        int H = 3 * g + 2 + c / 50, o = c % 50;
        if (kk < 300 * H){
          const float* w;
          switch (H){ case 2: w = w2; break; case 3: w = w3; break;
                      case 4: w = w4; break; case 5: w = w5; break;
                      case 6: w = w6; break; default: w = w7; break; }
          v = (_Float16)w[o * 300 * H + kk];
        }
      }
      Bp[idx] = v;
    }
    if (idx < 320){
      int g = idx / 160, c = idx - g * 160;
      float bv = 0.f;
      if (c < 150){
        int H = 3 * g + 2 + c / 50, o = c % 50;
        const float* cbp;
        switch (H){ case 2: cbp = c2; break; case 3: cbp = c3; break;
                    case 4: cbp = c4; break; case 5: cbp = c5; break;
                    case 6: cbp = c6; break; default: cbp = c7; break; }
        bv = cbp[o];
      }
      bias_p[idx] = bv;
    }
  } else if (blk < 3955){
    int idx = (blk - 3242) * 256 + tid;
    if (idx >= 1200 * 152) return;
    int row = idx / 152, col = idx - row * 152;
    wpad0[idx] = (col < 150) ? (_Float16)whh0[row * 150 + col] : (_Float16)0.f;
  } else if (blk < 4668){
    int idx = (blk - 3955) * 256 + tid;
    if (idx >= 1200 * 152) return;
    int row = idx / 152, col = idx - row * 152;
    wpad1[idx] = (col < 150) ? (_Float16)whh1[row * 150 + col] : (_Float16)0.f;
  } else if (blk < 6543){
    int idx = (blk - 4668) * 256 + tid;
    if (idx < 1600 * 300) ngram_u[idx] = 0u;
  } else if (blk < 6612){
    int idx = (blk - 6543) * 256 + tid;
    if (idx < NNODES) ecnt_u[idx] = 0u;
  } else {
    int idx = (blk - 6612) * 256 + tid;
    if (idx >= 16000 * 75) return;
    int row = idx / 75, q = idx - row * 75;
    const float4* t = (const float4*)tab;
    out1[idx] = t[x[row] * 75 + q];
  }
}

// ---------------- enc (fp16): enc[m][d] = tab[tok]+pos, pad rows zero -------
__global__ void gcnk_ench(const int* __restrict__ sx, const float* __restrict__ tab,
                          const float* __restrict__ pos, const int* __restrict__ sentlen,
                          _Float16* __restrict__ ench){
  int idx = blockIdx.x * 256 + threadIdx.x;
  if (idx >= MPAD * 75) return;
  int row = idx / 75, q = idx - row * 75;
  int d = q * 4;
  h4 o; o[0] = (_Float16)0.f; o[1] = (_Float16)0.f; o[2] = (_Float16)0.f; o[3] = (_Float16)0.f;
  if (row < MROWS){
    int n = row / 40, l = row - n * 40;
    int tok = sx[n * 40 + l];
    int p = (l < sentlen[n]) ? (l + 1) : 0;
    float4 a = *(const float4*)(tab + (size_t)tok * 300 + d);
    float4 b = *(const float4*)(pos + (size_t)p * 300 + d);
    o[0] = (_Float16)(a.x + b.x); o[1] = (_Float16)(a.y + b.y);
    o[2] = (_Float16)(a.z + b.z); o[3] = (_Float16)(a.w + b.w);
  }
  *(h4*)(ench + (size_t)row * 300 + d) = o;
}

// ---------------- fused conv GEMM via MFMA f16 (r7 config: proven 118us) ----
// BM=128, BN=160, BK=64. global_load_lds(16B) with XOR-swizzled SOURCE
// (T2 + rule #21); ds_read_b128 applies the same XOR. Grid (500,2).
// Conv experiments closed: XCD swizzle (r8/r9) and 2-phase BK=32 dbuf (r11)
// all regressed — the barrier's implicit vmcnt(0) drains the prefetch too,
// so implicit 4-blocks/CU overlap is already optimal at HIP source level.
__global__ __launch_bounds__(256)
void gcnk_convmfma(const _Float16* __restrict__ A, const _Float16* __restrict__ Bp,
                   const float* __restrict__ bias_p, unsigned int* __restrict__ ngram_u){
  __shared__ __align__(1024) char smem[36864];
  _Float16* Asm = (_Float16*)smem;             // [128][64] halfs (128B/row)
  _Float16* Bsm = (_Float16*)(smem + 16384);   // [160][64] halfs
  float* Cs = (float*)smem;                    // epilogue reuse: [128][33]
  const int tid = threadIdx.x;
  const int m0 = blockIdx.x * 128;
  const int grp = blockIdx.y;
  const char* Abase = (const char*)A;
  const char* Bbase = (const char*)(Bp + (size_t)grp * 160 * KSTRIDE);
  const int kmax = grp ? 2112 : 1216;          // heads 2-4 need K<=1200
  const int w = tid >> 6, lane = tid & 63;
  const int wm = (w >> 1) * 64, wn = (w & 1) * 80;
  const int fm = lane & 15, fq = lane >> 4;
  const int lrow = lane >> 3;                              // 0..7
  const int loff = (((lane & 7) ^ lrow) << 4);             // swizzled src byte in 128B row

  v4f acc[4][5] = {};

  for (int kc = 0; kc < kmax; kc += 64){
    // stage A: 16 issues of 1KB (8 rows x 128B); wave w does issues 4w..4w+3
    #pragma unroll
    for (int ii = 0; ii < 4; ii++){
      int i = w * 4 + ii;
      const char* g = Abase + (size_t)(m0 + i * 8 + lrow) * 600 + kc * 2 + loff;
      stage16(g, (char*)Asm + i * 1024, lane);
    }
    // stage B: 20 issues; wave w does issues 5w..5w+4
    #pragma unroll
    for (int jj = 0; jj < 5; jj++){
      int j = w * 5 + jj;
      const char* g = Bbase + (size_t)(j * 8 + lrow) * (KSTRIDE * 2) + kc * 2 + loff;
      stage16(g, (char*)Bsm + j * 1024, lane);
    }
    __syncthreads();
    #pragma unroll
    for (int ks = 0; ks < 2; ks++){
      const int axor = (ks * 64 + fq * 16) ^ ((fm & 7) << 4);
      v8h af[4], bf[5];
      #pragma unroll
      for (int mt = 0; mt < 4; mt++)
        af[mt] = *(const v8h*)((const char*)Asm + (wm + mt * 16 + fm) * 128 + axor);
      #pragma unroll
      for (int nt = 0; nt < 5; nt++)
        bf[nt] = *(const v8h*)((const char*)Bsm + (wn + nt * 16 + fm) * 128 + axor);
      #pragma unroll
      for (int mt = 0; mt < 4; mt++)
        #pragma unroll
        for (int nt = 0; nt < 5; nt++)
          acc[mt][nt] = __builtin_amdgcn_mfma_f32_16x16x32_f16(af[mt], bf[nt], acc[mt][nt], 0, 0, 0);
    }
    __syncthreads();
  }

  // epilogue: 5 passes of 32 cols through LDS; relu+window-max -> atomicMax
  for (int p = 0; p < 5; p++){
    __syncthreads();
    #pragma unroll
    for (int nt = 0; nt < 5; nt++){
      int cstart = wn + nt * 16;
      if ((cstart >> 5) == p){
        int co = cstart - p * 32 + fm;
        #pragma unroll
        for (int mt = 0; mt < 4; mt++)
          #pragma unroll
          for (int r = 0; r < 4; r++)
            Cs[(wm + mt * 16 + fq * 4 + r) * 33 + co] = acc[mt][nt][r];
      }
    }
    __syncthreads();
    if (tid < 128){
      int cl = tid & 31, si = tid >> 5;        // 4 sentences can touch a 128-row tile
      int col = p * 32 + cl;                   // group-local col
      if (col < 150){
        int H = 3 * grp + 2 + col / 50, lh = 41 - H;
        int sent = m0 / 40 + si;
        if (sent < 1600){
          int rlo = sent * 40; if (rlo < m0) rlo = m0;
          int rhi = sent * 40 + lh; if (rhi > m0 + 128) rhi = m0 + 128;
          if (rlo < rhi){
            float bv = bias_p[grp * 160 + col];
            float vmax = 0.f;
            for (int r = rlo; r < rhi; r++){
              float v = Cs[(r - m0) * 33 + cl] + bv;
              vmax = fmaxf(vmax, v);
            }
            atomicMax(ngram_u + sent * 300 + grp * 150 + col, __float_as_uint(vmax));
          }
        }
      }
    }
  }
}

// ---------------- gc0 GEMM: A fp16 [M][300] -> C fp16 [M][160] + bias -------
__global__ __launch_bounds__(256)
void gcnk_mgemmH(const _Float16* __restrict__ Ah, const float* __restrict__ Wt,
                 const float* __restrict__ b1, _Float16* __restrict__ Ch, int M, int N){
  const int K = 300;
  __shared__ __align__(16) _Float16 As[128 * 40];
  __shared__ __align__(16) _Float16 Bs[64 * 40];
  const int tid = threadIdx.x;
  const int m0 = blockIdx.x * 128, n0 = blockIdx.y * 64;
  const int w = tid >> 6, lane = tid & 63;
  const int wm = (w >> 1) * 64, wn = (w & 1) * 32;
  const int fm = lane & 15, fq = lane >> 4;
  v4f acc[4][2] = {};
  for (int ch = 0; ch < 10; ch++){
    int kc = ch * 32;
    #pragma unroll
    for (int j = 0; j < 2; j++){            // A stage: 128 rows x 32 halfs
      int u = tid + 256 * j;
      int row = u >> 2, cb = (u & 3) * 8;
      int gm = m0 + row, gk = kc + cb;
      v8h vv;
      if (gm < M && gk + 8 <= K){
        const char* p = (const char*)(Ah + (size_t)gm * 300 + gk);
        union { uint2 u2[2]; v8h v; } t;
        t.u2[0] = *(const uint2*)p; t.u2[1] = *(const uint2*)(p + 8);
        vv = t.v;
      } else {
        #pragma unroll
        for (int e = 0; e < 8; e++)
          vv[e] = (gm < M && gk + e < K) ? Ah[(size_t)gm * 300 + gk + e] : (_Float16)0.f;
      }
      *(v8h*)(As + row * 40 + cb) = vv;
    }
    {                                        // B stage: 64 rows x 32 halfs (fp32 W)
      int row = tid >> 2, cb = (tid & 3) * 8;
      int gn = n0 + row, gk = kc + cb;
      v8h vv;
      if (gn < N && gk + 8 <= K){
        const float2* p = (const float2*)(Wt + (size_t)gn * K + gk);
        float2 q0 = p[0], q1 = p[1], q2 = p[2], q3 = p[3];
        vv[0] = (_Float16)q0.x; vv[1] = (_Float16)q0.y;
        vv[2] = (_Float16)q1.x; vv[3] = (_Float16)q1.y;
        vv[4] = (_Float16)q2.x; vv[5] = (_Float16)q2.y;
        vv[6] = (_Float16)q3.x; vv[7] = (_Float16)q3.y;
      } else {
        #pragma unroll
        for (int e = 0; e < 8; e++)
          vv[e] = (gn < N && gk + e < K) ? (_Float16)Wt[(size_t)gn * K + gk + e] : (_Float16)0.f;
      }
      *(v8h*)(Bs + row * 40 + cb) = vv;
    }
    __syncthreads();
    v8h af[4], bf[2];
    #pragma unroll
    for (int mt = 0; mt < 4; mt++)
      af[mt] = *(const v8h*)(As + (wm + mt * 16 + fm) * 40 + fq * 8);
    #pragma unroll
    for (int nt = 0; nt < 2; nt++)
      bf[nt] = *(const v8h*)(Bs + (wn + nt * 16 + fm) * 40 + fq * 8);
    #pragma unroll
    for (int mt = 0; mt < 4; mt++)
      #pragma unroll
      for (int nt = 0; nt < 2; nt++)
        acc[mt][nt] = __builtin_amdgcn_mfma_f32_16x16x32_f16(af[mt], bf[nt], acc[mt][nt], 0, 0, 0);
    __syncthreads();
  }
  #pragma unroll
  for (int nt = 0; nt < 2; nt++){
    int gn = n0 + wn + nt * 16 + fm;
    if (gn >= N) continue;
    float badd = b1[gn];
    #pragma unroll
    for (int mt = 0; mt < 4; mt++)
      #pragma unroll
      for (int r = 0; r < 4; r++){
        int gm = m0 + wm + mt * 16 + fq * 4 + r;
        if (gm < M) Ch[(size_t)gm * 160 + gn] = (_Float16)(acc[mt][nt][r] + badd);
      }
  }
}

// ---------------- gc1/gc2 GEMM: A fp16 [M][160](150 used) -> C fp16 [M][160]
__global__ __launch_bounds__(256)
void gcnk_mgemmHX(const _Float16* __restrict__ Ah, const float* __restrict__ Wt,
                  _Float16* __restrict__ Ch, int M){
  const int K = 150, N = 150;
  __shared__ __align__(16) _Float16 As[128 * 40];
  __shared__ __align__(16) _Float16 Bs[64 * 40];
  const int tid = threadIdx.x;
  const int m0 = blockIdx.x * 128, n0 = blockIdx.y * 64;
  const int w = tid >> 6, lane = tid & 63;
  const int wm = (w >> 1) * 64, wn = (w & 1) * 32;
  const int fm = lane & 15, fq = lane >> 4;
  v4f acc[4][2] = {};
  for (int ch = 0; ch < 5; ch++){          // ceil(150/32)=5 chunks
    int kc = ch * 32;
    #pragma unroll
    for (int j = 0; j < 2; j++){            // A stage: 128 rows x 32 halfs
      int u = tid + 256 * j;
      int row = u >> 2, cb = (u & 3) * 8;
      int gm = m0 + row, gk = kc + cb;
      v8h vv;
      if (gm < M && gk + 8 <= K){
        const char* p = (const char*)(Ah + (size_t)gm * 160 + gk);
        union { uint2 u2[2]; v8h v; } t;
        t.u2[0] = *(const uint2*)p; t.u2[1] = *(const uint2*)(p + 8);
        vv = t.v;
      } else {
        #pragma unroll
        for (int e = 0; e < 8; e++)
          vv[e] = (gm < M && gk + e < K) ? Ah[(size_t)gm * 160 + gk + e] : (_Float16)0.f;
      }
      *(v8h*)(As + row * 40 + cb) = vv;
    }
    {                                        // B stage: 64 rows x 32 halfs (fp32 W)
      int row = tid >> 2, cb = (tid & 3) * 8;
      int gn = n0 + row, gk = kc + cb;
      v8h vv;
      if (gn < N && gk + 8 <= K){
        const float2* p = (const float2*)(Wt + (size_t)gn * K + gk);
        float2 q0 = p[0], q1 = p[1], q2 = p[2], q3 = p[3];
        vv[0] = (_Float16)q0.x; vv[1] = (_Float16)q0.y;
        vv[2] = (_Float16)q1.x; vv[3] = (_Float16)q1.y;
        vv[4] = (_Float16)q2.x; vv[5] = (_Float16)q2.y;
        vv[6] = (_Float16)q3.x; vv[7] = (_Float16)q3.y;
      } else {
        #pragma unroll
        for (int e = 0; e < 8; e++)
          vv[e] = (gn < N && gk + e < K) ? (_Float16)Wt[(size_t)gn * K + gk + e] : (_Float16)0.f;
      }
      *(v8h*)(Bs + row * 40 + cb) = vv;
    }
    __syncthreads();
    v8h af[4], bf[2];
    #pragma unroll
    for (int mt = 0; mt < 4; mt++)
      af[mt] = *(const v8h*)(As + (wm + mt * 16 + fm) * 40 + fq * 8);
    #pragma unroll
    for (int nt = 0; nt < 2; nt++)
      bf[nt] = *(const v8h*)(Bs + (wn + nt * 16 + fm) * 40 + fq * 8);
    #pragma unroll
    for (int mt = 0; mt < 4; mt++)
      #pragma unroll
      for (int nt = 0; nt < 2; nt++)
        acc[mt][nt] = __builtin_amdgcn_mfma_f32_16x16x32_f16(af[mt], bf[nt], acc[mt][nt], 0, 0, 0);
    __syncthreads();
  }
  #pragma unroll
  for (int nt = 0; nt < 2; nt++){
    int gn = n0 + wn + nt * 16 + fm;
    if (gn >= N) continue;
    #pragma unroll
    for (int mt = 0; mt < 4; mt++)
      #pragma unroll
      for (int r = 0; r < 4; r++){
        int gm = m0 + wm + mt * 16 + fq * 4 + r;
        if (gm < M) Ch[(size_t)gm * 160 + gn] = (_Float16)acc[mt][nt][r];
      }
  }
}

// ---------------- flexible small GEMM with fused gather/concat/mask/pos -----
__global__ __launch_bounds__(256)
void gcnk_mgemmF(const float* __restrict__ A1, const int* __restrict__ mapA,
                 const float* __restrict__ A2, const int* __restrict__ mapB,
                 const int* __restrict__ glen, int usemask,
                 const float* __restrict__ apos,
                 const float* __restrict__ Wt, const float* __restrict__ b1,
                 const float* __restrict__ b2, float* __restrict__ C,
                 int M, int N, int K){
  const int BM = 64, WMT = 2, WNT = 2;
  __shared__ __align__(16) _Float16 As[BM * 40];
  __shared__ __align__(16) _Float16 Bs[64 * 40];
  const int tid = threadIdx.x;
  const int m0 = blockIdx.x * BM, n0 = blockIdx.y * 64;
  const int w = tid >> 6, lane = tid & 63;
  const int wm = (w >> 1) * (WMT * 16), wn = (w & 1) * (WNT * 16);
  const int fm = lane & 15, fq = lane >> 4;
  v4f acc[WMT][WNT] = {};
  const int nch = (K + 31) >> 5;
  for (int ch = 0; ch < nch; ch++){
    int kc = ch * 32;
    {                                        // A stage: 64 rows x 32 halfs
      int row = tid >> 2, cb = (tid & 3) * 8;
      int gm = m0 + row, gk = kc + cb;
      v8h vv;
      bool ok = (gm < M);
      if (ok && usemask){
        int b = gm / 50;
        if (gm - b * 50 >= glen[b]) ok = false;
      }
      if (!ok){
        #pragma unroll
        for (int e = 0; e < 8; e++) vv[e] = (_Float16)0.f;
      } else if (!A2){
        int r = mapA ? mapA[gm] : gm;
        const float* base = A1 + (size_t)r * K;
        if (gk + 8 <= K){
          const float2* p = (const float2*)(base + gk);
          float2 q0 = p[0], q1 = p[1], q2 = p[2], q3 = p[3];
          if (apos){
            const float2* a2 = (const float2*)(apos + (size_t)(gm % 50) * K + gk);
            float2 r0 = a2[0], r1 = a2[1], r2 = a2[2], r3 = a2[3];
            q0.x += r0.x; q0.y += r0.y; q1.x += r1.x; q1.y += r1.y;
            q2.x += r2.x; q2.y += r2.y; q3.x += r3.x; q3.y += r3.y;
          }
          vv[0] = (_Float16)q0.x; vv[1] = (_Float16)q0.y;
          vv[2] = (_Float16)q1.x; vv[3] = (_Float16)q1.y;
          vv[4] = (_Float16)q2.x; vv[5] = (_Float16)q2.y;
          vv[6] = (_Float16)q3.x; vv[7] = (_Float16)q3.y;
        } else {
          #pragma unroll
          for (int e = 0; e < 8; e++){
            int c = gk + e;
            float vf = (c < K) ? base[c] : 0.f;
            if (apos && c < K) vf += apos[(size_t)(gm % 50) * K + c];
            vv[e] = (_Float16)vf;
          }
        }
      } else {
        int rA = mapA ? mapA[gm] : gm;
        int rB = mapB ? mapB[gm] : gm;
        const float* pa = A1 + (size_t)rA * 150;
        const float* pb = A2 + (size_t)rB * 150;
        if (gk + 8 <= 150){
          const float2* p = (const float2*)(pa + gk);
          float2 q0 = p[0], q1 = p[1], q2 = p[2], q3 = p[3];
          vv[0] = (_Float16)q0.x; vv[1] = (_Float16)q0.y;
          vv[2] = (_Float16)q1.x; vv[3] = (_Float16)q1.y;
          vv[4] = (_Float16)q2.x; vv[5] = (_Float16)q2.y;
          vv[6] = (_Float16)q3.x; vv[7] = (_Float16)q3.y;
        } else if (gk >= 152 && gk + 8 <= K){
          const float2* p = (const float2*)(pb + gk - 150);
          float2 q0 = p[0], q1 = p[1], q2 = p[2], q3 = p[3];
          vv[0] = (_Float16)q0.x; vv[1] = (_Float16)q0.y;
          vv[2] = (_Float16)q1.x; vv[3] = (_Float16)q1.y;
          vv[4] = (_Float16)q2.x; vv[5] = (_Float16)q2.y;
          vv[6] = (_Float16)q3.x; vv[7] = (_Float16)q3.y;
        } else {
          #pragma unroll
          for (int e = 0; e < 8; e++){
            int c = gk + e;
            vv[e] = (c < 150) ? (_Float16)pa[c]
                  : ((c < K) ? (_Float16)pb[c - 150] : (_Float16)0.f);
          }
        }
      }
      *(v8h*)(As + row * 40 + cb) = vv;
    }
    {                                        // B stage: 64 rows x 32 halfs
      int row = tid >> 2, cb = (tid & 3) * 8;
      int gn = n0 + row, gk = kc + cb;
      v8h vv;
      if (gn < N && gk + 8 <= K){
        const float2* p = (const float2*)(Wt + (size_t)gn * K + gk);
        float2 q0 = p[0], q1 = p[1], q2 = p[2], q3 = p[3];
        vv[0] = (_Float16)q0.x; vv[1] = (_Float16)q0.y;
        vv[2] = (_Float16)q1.x; vv[3] = (_Float16)q1.y;
        vv[4] = (_Float16)q2.x; vv[5] = (_Float16)q2.y;
        vv[6] = (_Float16)q3.x; vv[7] = (_Float16)q3.y;
      } else {
        #pragma unroll
        for (int e = 0; e < 8; e++)
          vv[e] = (gn < N && gk + e < K) ? (_Float16)Wt[(size_t)gn * K + gk + e] : (_Float16)0.f;
      }
      *(v8h*)(Bs + row * 40 + cb) = vv;
    }
    __syncthreads();
    v8h af[WMT], bf[WNT];
    #pragma unroll
    for (int mt = 0; mt < WMT; mt++)
      af[mt] = *(const v8h*)(As + (wm + mt * 16 + fm) * 40 + fq * 8);
    #pragma unroll
    for (int nt = 0; nt < WNT; nt++)
      bf[nt] = *(const v8h*)(Bs + (wn + nt * 16 + fm) * 40 + fq * 8);
    #pragma unroll
    for (int mt = 0; mt < WMT; mt++)
      #pragma unroll
      for (int nt = 0; nt < WNT; nt++)
        acc[mt][nt] = __builtin_amdgcn_mfma_f32_16x16x32_f16(af[mt], bf[nt], acc[mt][nt], 0, 0, 0);
    __syncthreads();
  }
  #pragma unroll
  for (int nt = 0; nt < WNT; nt++){
    int gn = n0 + wn + nt * 16 + fm;
    if (gn >= N) continue;
    float badd = (b1 ? b1[gn] : 0.f) + (b2 ? b2[gn] : 0.f);
    #pragma unroll
    for (int mt = 0; mt < WMT; mt++)
      #pragma unroll
      for (int r = 0; r < 4; r++){
        int gm = m0 + wm + mt * 16 + fq * 4 + r;
        if (gm < M) C[(size_t)gm * N + gn] = acc[mt][nt][r] + badd;
      }
  }
}

// ---------------- paired variant: blockIdx.z selects one of two param sets --
struct FArgs {
  const float* A1; const int* mapA;
  const float* A2; const int* mapB;
  const float* Wt; const float* b1; const float* b2;
  float* C;
};

__global__ __launch_bounds__(256)
void gcnk_mgemmF2(FArgs pa, FArgs pb, int M, int N, int K){
  const int BM = 64, WMT = 2, WNT = 2;
  __shared__ __align__(16) _Float16 As[BM * 40];
  __shared__ __align__(16) _Float16 Bs[64 * 40];
  const FArgs P = blockIdx.z ? pb : pa;
  const int tid = threadIdx.x;
  const int m0 = blockIdx.x * BM, n0 = blockIdx.y * 64;
  const int w = tid >> 6, lane = tid & 63;
  const int wm = (w >> 1) * (WMT * 16), wn = (w & 1) * (WNT * 16);
  const int fm = lane & 15, fq = lane >> 4;
  v4f acc[WMT][WNT] = {};
  const int nch = (K + 31) >> 5;
  for (int ch = 0; ch < nch; ch++){
    int kc = ch * 32;
    {                                        // A stage: 64 rows x 32 halfs
      int row = tid >> 2, cb = (tid & 3) * 8;
      int gm = m0 + row, gk = kc + cb;
      v8h vv;
      if (gm >= M){
        #pragma unroll
        for (int e = 0; e < 8; e++) vv[e] = (_Float16)0.f;
      } else if (!P.A2){
        int r = P.mapA ? P.mapA[gm] : gm;
        const float* base = P.A1 + (size_t)r * K;
        if (gk + 8 <= K){
          const float2* p = (const float2*)(base + gk);
          float2 q0 = p[0], q1 = p[1], q2 = p[2], q3 = p[3];
          vv[0] = (_Float16)q0.x; vv[1] = (_Float16)q0.y;
          vv[2] = (_Float16)q1.x; vv[3] = (_Float16)q1.y;
          vv[4] = (_Float16)q2.x; vv[5] = (_Float16)q2.y;
          vv[6] = (_Float16)q3.x; vv[7] = (_Float16)q3.y;
        } else {
          #pragma unroll
          for (int e = 0; e < 8; e++)
            vv[e] = (gk + e < K) ? (_Float16)base[gk + e] : (_Float16)0.f;
        }
      } else {
        int rA = P.mapA ? P.mapA[gm] : gm;
        int rB = P.mapB ? P.mapB[gm] : gm;
        const float* paa = P.A1 + (size_t)rA * 150;
        const float* pbb = P.A2 + (size_t)rB * 150;
        if (gk + 8 <= 150){
          const float2* p = (const float2*)(paa + gk);
          float2 q0 = p[0], q1 = p[1], q2 = p[2], q3 = p[3];
          vv[0] = (_Float16)q0.x; vv[1] = (_Float16)q0.y;
          vv[2] = (_Float16)q1.x; vv[3] = (_Float16)q1.y;
          vv[4] = (_Float16)q2.x; vv[5] = (_Float16)q2.y;
          vv[6] = (_Float16)q3.x; vv[7] = (_Float16)q3.y;
        } else if (gk >= 152 && gk + 8 <= K){
          const float2* p = (const float2*)(pbb + gk - 150);
          float2 q0 = p[0], q1 = p[1], q2 = p[2], q3 = p[3];
          vv[0] = (_Float16)q0.x; vv[1] = (_Float16)q0.y;
          vv[2] = (_Float16)q1.x; vv[3] = (_Float16)q1.y;
          vv[4] = (_Float16)q2.x; vv[5] = (_Float16)q2.y;
          vv[6] = (_Float16)q3.x; vv[7] = (_Float16)q3.y;
        } else {
          #pragma unroll
          for (int e = 0; e < 8; e++){
            int c = gk + e;
            vv[e] = (c < 150) ? (_Float16)paa[c]
                  : ((c < K) ? (_Float16)pbb[c - 150] : (_Float16)0.f);
          }
        }
      }
      *(v8h*)(As + row * 40 + cb) = vv;
    }
    {                                        // B stage: 64 rows x 32 halfs
      int row = tid >> 2, cb = (tid & 3) * 8;
      int gn = n0 + row, gk = kc + cb;
      v8h vv;
      if (gn < N && gk + 8 <= K){
        const float2* p = (const float2*)(P.Wt + (size_t)gn * K + gk);
        float2 q0 = p[0], q1 = p[1], q2 = p[2], q3 = p[3];
        vv[0] = (_Float16)q0.x; vv[1] = (_Float16)q0.y;
        vv[2] = (_Float16)q1.x; vv[3] = (_Float16)q1.y;
        vv[4] = (_Float16)q2.x; vv[5] = (_Float16)q2.y;
        vv[6] = (_Float16)q3.x; vv[7] = (_Float16)q3.y;
      } else {
        #pragma unroll
        for (int e = 0; e < 8; e++)
          vv[e] = (gn < N && gk + e < K) ? (_Float16)P.Wt[(size_t)gn * K + gk + e] : (_Float16)0.f;
      }
      *(v8h*)(Bs + row * 40 + cb) = vv;
    }
    __syncthreads();
    v8h af[WMT], bf[WNT];
    #pragma unroll
    for (int mt = 0; mt < WMT; mt++)
      af[mt] = *(const v8h*)(As + (wm + mt * 16 + fm) * 40 + fq * 8);
    #pragma unroll
    for (int nt = 0; nt < WNT; nt++)
      bf[nt] = *(const v8h*)(Bs + (wn + nt * 16 + fm) * 40 + fq * 8);
    #pragma unroll
    for (int mt = 0; mt < WMT; mt++)
      #pragma unroll
      for (int nt = 0; nt < WNT; nt++)
        acc[mt][nt] = __builtin_amdgcn_mfma_f32_16x16x32_f16(af[mt], bf[nt], acc[mt][nt], 0, 0, 0);
    __syncthreads();
  }
  #pragma unroll
  for (int nt = 0; nt < WNT; nt++){
    int gn = n0 + wn + nt * 16 + fm;
    if (gn >= N) continue;
    float badd = (P.b1 ? P.b1[gn] : 0.f) + (P.b2 ? P.b2[gn] : 0.f);
    #pragma unroll
    for (int mt = 0; mt < WMT; mt++)
      #pragma unroll
      for (int r = 0; r < 4; r++){
        int gm = m0 + wm + mt * 16 + fq * 4 + r;
        if (gm < M) P.C[(size_t)gm * N + gn] = acc[mt][nt][r] + badd;
      }
  }
}

// ---------------- node feature assembly, fp16 out [17600 x 300] -------------
__global__ void gcnk_nodes_in_h(const int* __restrict__ x, const float* __restrict__ tab,
                                const float* __restrict__ cnnf, const float* __restrict__ lstmf,
                                h2* __restrict__ out){
  int idx = blockIdx.x * 256 + threadIdx.x;
  if (idx >= NNODES * 150) return;
  int nrow = idx / 150, q = idx - nrow * 150;
  int d = q * 2;
  int b = nrow / 550, j = nrow - b * 550;
  float2 v;
  if (j < 500) v = *(const float2*)(tab + (size_t)x[b * 500 + j] * 300 + d);
  else {
    int r = b * 50 + (j - 500);
    if (d < 150) v = *(const float2*)(cnnf + (size_t)r * 150 + d);
    else         v = *(const float2*)(lstmf + (size_t)r * 150 + d - 150);
  }
  h2 o; o[0] = (_Float16)v.x; o[1] = (_Float16)v.y;
  out[idx] = o;
}

// ---------------- LSTM recurrence: weights in VGPRs, h fp16 in LDS ----------
__global__ __launch_bounds__(640)
void gcnk_lstm(const float* __restrict__ xf, const float* __restrict__ xr,
               const _Float16* __restrict__ wpad, float* __restrict__ fo,
               float* __restrict__ ro){
  int b = blockIdx.x >> 1, dir = blockIdx.x & 1;
  const float* xih = dir ? xr : xf;
  float* out = dir ? ro : fo;
  __shared__ __align__(16) _Float16 hh[160];
  __shared__ float gates[600];
  const int tid = threadIdx.x;

  h2 w[76];
  if (tid < 600){
    const h2* wrow = (const h2*)(wpad + ((size_t)dir * 600 + tid) * 152);
    #pragma unroll
    for (int j = 0; j < 76; j++) w[j] = wrow[j];
  }
  for (int u = tid; u < 160; u += 640) hh[u] = (_Float16)0.f;
  float creg = 0.f;
  __syncthreads();

  for (int t = 0; t < 50; t++){
    if (tid < 600){
      float acc = xih[(b * 50 + t) * 600 + tid];
      float a0 = 0.f, a1 = 0.f, a2 = 0.f, a3 = 0.f;   // break the dep chain 4-way
      #pragma unroll
      for (int j = 0; j < 19; j++){
        union { float4 f; h2 h[4]; } u;
        u.f = *(const float4*)(hh + j * 8);
        a0 = fdot2_(w[4 * j + 0], u.h[0], a0);
        a1 = fdot2_(w[4 * j + 1], u.h[1], a1);
        a2 = fdot2_(w[4 * j + 2], u.h[2], a2);
        a3 = fdot2_(w[4 * j + 3], u.h[3], a3);
      }
      gates[tid] = acc + ((a0 + a1) + (a2 + a3));
    }
    __syncthreads();
    if (tid < 150){
      float ig = sigm(gates[tid]);
      float fg = sigm(gates[150 + tid]);
      float gg = tanhf(gates[300 + tid]);
      float og = sigm(gates[450 + tid]);
      creg = fg * creg + ig * gg;
      float hn = og * tanhf(creg);
      hh[tid] = (_Float16)hn;
      out[(b * 50 + t) * 150 + tid] = hn;
    }
    __syncthreads();
  }
}

// ---------------- GCN: CSR build (counting sort by dst) ---------------------
__global__ void gcnk_hist(const int* __restrict__ ei, int* __restrict__ ecnt){
  int e = blockIdx.x * 256 + threadIdx.x;
  if (e < EDGES) atomicAdd(&ecnt[ei[EDGES + e]], 1);
}

// fast single-block scan: serial 18/thread + wave shfl scan + 16-entry scan
// also emits dis[i] = rsqrt(deg+1) (fused dis2)
__global__ __launch_bounds__(1024)
void gcnk_scan(const int* __restrict__ ecnt, int* __restrict__ eoff,
               int* __restrict__ ecur, float* __restrict__ dis){
  __shared__ int wsum[16];
  int tid = threadIdx.x;
  int base = tid * 18;
  int pre[18];
  int s = 0;
  #pragma unroll
  for (int i = 0; i < 18; i++){
    int idx = base + i;
    int c = (idx < NNODES) ? ecnt[idx] : 0;
    if (idx < NNODES) dis[idx] = rsqrtf((float)(c + 1));
    pre[i] = s; s += c;
  }
  int lane = tid & 63, wid = tid >> 6;
  int run = s;
  #pragma unroll
  for (int off = 1; off < 64; off <<= 1){
    int y = __shfl_up(run, off, 64);
    if (lane >= off) run += y;
  }
  if (lane == 63) wsum[wid] = run;
  __syncthreads();
  if (tid == 0){
    int a = 0;
    #pragma unroll
    for (int i = 0; i < 16; i++){ int t2 = wsum[i]; wsum[i] = a; a += t2; }
  }
  __syncthreads();
  int excl = wsum[wid] + run - s;
  #pragma unroll
  for (int i = 0; i < 18; i++){
    int idx = base + i;
    if (idx < NNODES){
      int e = excl + pre[i];
      eoff[idx] = e; ecur[idx] = e;
    }
  }
}

__global__ void gcnk_scatter(const int* __restrict__ ei, int* __restrict__ ecur,
                             int* __restrict__ esrc){
  int e = blockIdx.x * 256 + threadIdx.x;
  if (e < EDGES){
    int d = ei[EDGES + e];
    int p = atomicAdd(&ecur[d], 1);
    esrc[p] = ei[e];
  }
}

// ---------------- GCN aggregation: fp16 gather + fused bias/elu epilogue ----
// outh=1: write fp16 [d][160]; outh=0: write fp32 [d][150].
__global__ __launch_bounds__(128)
void gcnk_aggcsr_h(const int* __restrict__ eoff, const int* __restrict__ ecnt,
                   const int* __restrict__ esrc, const float* __restrict__ dis,
                   const _Float16* __restrict__ xw, const float* __restrict__ bias,
                   void* __restrict__ out, int doelu, int outh){
  int d = blockIdx.x, t = threadIdx.x;
  float dd = dis[d];
  bool act = t < 75;
  float ax0 = 0.f, ay0 = 0.f, ax1 = 0.f, ay1 = 0.f;
  if (act){
    h2 v = *(const h2*)(xw + (size_t)d * 160 + 2 * t);
    ax0 = (float)v[0] * dd; ay0 = (float)v[1] * dd;
  }
  int beg = eoff[d], end = beg + ecnt[d];
  int j = beg;
  for (; j + 1 < end; j += 2){
    int s0 = esrc[j], s1 = esrc[j + 1];
    float d0 = dis[s0], d1 = dis[s1];
    if (act){
      h2 v0 = *(const h2*)(xw + (size_t)s0 * 160 + 2 * t);
      h2 v1 = *(const h2*)(xw + (size_t)s1 * 160 + 2 * t);
      ax0 += (float)v0[0] * d0; ay0 += (float)v0[1] * d0;
      ax1 += (float)v1[0] * d1; ay1 += (float)v1[1] * d1;
    }
  }
  if (j < end){
    int s = esrc[j];
    float ds_ = dis[s];
    if (act){
      h2 v = *(const h2*)(xw + (size_t)s * 160 + 2 * t);
      ax0 += (float)v[0] * ds_; ay0 += (float)v[1] * ds_;
    }
  }
  if (act){
    float o0 = (ax0 + ax1) * dd + bias[2 * t];
    float o1 = (ay0 + ay1) * dd + bias[2 * t + 1];
    if (doelu){
      o0 = (o0 > 0.f) ? o0 : expm1f(o0);
      o1 = (o1 > 0.f) ? o1 : expm1f(o1);
    }
    if (outh){
      h2 o; o[0] = (_Float16)o0; o[1] = (_Float16)o1;
      *(h2*)((_Float16*)out + (size_t)d * 160 + 2 * t) = o;
    } else {
      *(float2*)((float*)out + (size_t)d * 150 + 2 * t) = make_float2(o0, o1);
    }
  }
}

// ============================================================================
extern "C" void kernel_launch(void* const* d_in, const int* in_sizes, int n_in,
                              void* d_out, int out_size, void* d_ws, size_t ws_size,
                              hipStream_t stream){
  (void)in_sizes; (void)n_in; (void)out_size; (void)ws_size;

  char* wsb = (char*)d_ws;
  size_t off = 0;
  auto alloc = [&](size_t bytes) -> void* {
    void* p = wsb + off;
    off = (off + bytes + 255) & ~(size_t)255;
    return p;
  };
  float* pos_tab  = (float*)alloc(513 * 300 * 4);
  int*   sentlen  = (int*)alloc(1600 * 4);
  int*   glen     = (int*)alloc(32 * 4);
  int*   rowmap   = (int*)alloc(1600 * 4);
  float* ngram    = (float*)alloc(1600 * 300 * 4);
  float* cnn_feat = (float*)alloc(1600 * 150 * 4);
  float* xih_f    = (float*)alloc(1600 * 600 * 4);
  float* xih_r    = (float*)alloc(1600 * 600 * 4);
  float* f0       = (float*)alloc(1600 * 150 * 4);
  float* r0       = (float*)alloc(1600 * 150 * 4);
  float* f1       = (float*)alloc(1600 * 150 * 4);
  float* r1       = (float*)alloc(1600 * 150 * 4);
  float* lstm_ft  = (float*)alloc(1600 * 150 * 4);
  h2*    nodes_ih = (h2*)alloc((size_t)NNODES * 150 * 4);   // fp16 [NNODES][300]
  _Float16* nodesh= (_Float16*)alloc((size_t)NNODES * 160 * 2); // fp16 [NNODES][160]
  float* dis      = (float*)alloc(NNODES * 4);
  _Float16* xwh   = (_Float16*)alloc((size_t)NNODES * 160 * 2);
  _Float16* ench  = (_Float16*)alloc((size_t)MPAD * 300 * 2);
  _Float16* Bp    = (_Float16*)alloc((size_t)2 * 160 * KSTRIDE * 2);
  float* bias_p   = (float*)alloc(320 * 4);
  _Float16* wpad0 = (_Float16*)alloc(1200 * 152 * 2);
  _Float16* wpad1 = (_Float16*)alloc(1200 * 152 * 2);
  int*   ecnt     = (int*)alloc(NNODES * 4);
  int*   eoff     = (int*)alloc(NNODES * 4);
  int*   ecur     = (int*)alloc(NNODES * 4);
  int*   esrc     = (int*)alloc(EDGES * 4);

  const int*   x   = (const int*)d_in[0];
  const int*   sx  = (const int*)d_in[1];
  const int*   ei  = (const int*)d_in[2];
  const float* tab = (const float*)d_in[3];
  const float *cw[6], *cb[6];
  for (int h = 0; h < 6; h++){ cw[h] = (const float*)d_in[4 + 2 * h]; cb[h] = (const float*)d_in[5 + 2 * h]; }
  const float* cnnw = (const float*)d_in[16]; const float* cnnb = (const float*)d_in[17];
  const float* wih0 = (const float*)d_in[18]; const float* whh0 = (const float*)d_in[19];
  const float* bih0 = (const float*)d_in[20]; const float* bhh0 = (const float*)d_in[21];
  const float* wih1 = (const float*)d_in[22]; const float* whh1 = (const float*)d_in[23];
  const float* bih1 = (const float*)d_in[24]; const float* bhh1 = (const float*)d_in[25];
  const float* lpw  = (const float*)d_in[26]; const float* lpb  = (const float*)d_in[27];
  const float* g0w  = (const float*)d_in[28]; const float* g0b  = (const float*)d_in[29];
  const float* g1w  = (const float*)d_in[30]; const float* g1b  = (const float*)d_in[31];
  const float* g2w  = (const float*)d_in[32]; const float* g2b  = (const float*)d_in[33];

  float* out0 = (float*)d_out;
  float4* out1 = (float4*)((float*)d_out + OUT0SZ);

  // flexible small GEMM (M=1600)
  auto mgemmF = [&](const float* A1, const int* mapA, const float* A2, const int* mapB,
                    const int* gl, int um, const float* apos, const float* W,
                    const float* b1, const float* b2, float* C, int N, int K){
    dim3 g(25, (N + 63) / 64);
    gcnk_mgemmF<<<g, 256, 0, stream>>>(A1, mapA, A2, mapB, gl, um, apos, W, b1, b2, C, 1600, N, K);
  };

  // ---- pipeline ----
  gcnk_prep2<<<1, 1024, 0, stream>>>(sx, sentlen, glen, rowmap);
  gcnk_mergedprep<<<11300, 256, 0, stream>>>(
      pos_tab, cw[0], cw[1], cw[2], cw[3], cw[4], cw[5],
      cb[0], cb[1], cb[2], cb[3], cb[4], cb[5], Bp, bias_p,
      whh0, wpad0, whh1, wpad1, (unsigned int*)ngram, (unsigned int*)ecnt,
      x, tab, out1);
  gcnk_ench<<<(MPAD * 75 + 255) / 256, 256, 0, stream>>>(sx, tab, pos_tab, sentlen, ench);

  // conv: r7 config (proven fastest), 2-D grid
  {
    dim3 g(500, 2);
    gcnk_convmfma<<<g, 256, 0, stream>>>(ench, Bp, bias_p, (unsigned int*)ngram);
  }

  // cnn_proj with POS-add fused into A-stage
  mgemmF(ngram, nullptr, nullptr, nullptr, nullptr, 0, pos_tab,
         cnnw, cnnb, nullptr, cnn_feat, 150, 300);

  // BiLSTM layer 0: fwd+rev xih in ONE z=2 launch (permute fused into A-load)
  {
    FArgs pa{cnn_feat, nullptr, nullptr, nullptr, wih0,             bih0,       bhh0,       xih_f};
    FArgs pb{cnn_feat, rowmap,  nullptr, nullptr, wih0 + 600 * 150, bih0 + 600, bhh0 + 600, xih_r};
    dim3 g(25, 10, 2);
    gcnk_mgemmF2<<<g, 256, 0, stream>>>(pa, pb, 1600, 600, 150);
  }
  gcnk_lstm<<<64, 640, 0, stream>>>(xih_f, xih_r, wpad0, f0, r0);

  // BiLSTM layer 1: fwd+rev xih in ONE z=2 launch (concat fused into A-load)
  {
    FArgs pa{f0, nullptr, r0, rowmap,  wih1,             bih1,       bhh1,       xih_f};
    FArgs pb{f0, rowmap,  r0, nullptr, wih1 + 600 * 300, bih1 + 600, bhh1 + 600, xih_r};
    dim3 g(25, 10, 2);
    gcnk_mgemmF2<<<g, 256, 0, stream>>>(pa, pb, 1600, 600, 300);
  }
  gcnk_lstm<<<64, 640, 0, stream>>>(xih_f, xih_r, wpad1, f1, r1);

  // masked projection (concat + mask fused into A-load)
  mgemmF(f1, nullptr, r1, rowmap, glen, 1, nullptr, lpw, lpb, nullptr, lstm_ft, 150, 300);

  // node features (fp16, gathered once) + gc0 (fp16-A GEMM -> fp16 nodesh)
  gcnk_nodes_in_h<<<(NNODES * 150 + 255) / 256, 256, 0, stream>>>(x, tab, cnn_feat, lstm_ft, nodes_ih);
  {
    dim3 g(138, 3);
    gcnk_mgemmH<<<g, 256, 0, stream>>>((const _Float16*)nodes_ih, g0w, g0b, nodesh, NNODES, 150);
  }

  // CSR build (once, reused by both GCN layers); dis fused into scan
  gcnk_hist<<<2200, 256, 0, stream>>>(ei, ecnt);
  gcnk_scan<<<1, 1024, 0, stream>>>(ecnt, eoff, ecur, dis);
  gcnk_scatter<<<2200, 256, 0, stream>>>(ei, ecur, esrc);

  // gc1 + elu (fp16 A, fp16 xw gather, fused bias+elu epilogue -> fp16 nodesh)
  {
    dim3 g(138, 3);
    gcnk_mgemmHX<<<g, 256, 0, stream>>>(nodesh, g1w, xwh, NNODES);
  }
  gcnk_aggcsr_h<<<NNODES, 128, 0, stream>>>(eoff, ecnt, esrc, dis, xwh, g1b, nodesh, 1, 1);

  // gc2 -> output 0 (fp16 A, fused bias epilogue -> fp32 out0)
  {
    dim3 g(138, 3);
    gcnk_mgemmHX<<<g, 256, 0, stream>>>(nodesh, g2w, xwh, NNODES);
  }
  gcnk_aggcsr_h<<<NNODES, 128, 0, stream>>>(eoff, ecnt, esrc, dis, xwh, g2b, out0, 0, 0);
}

// Round 13
// 754.558 us; speedup vs baseline: 1.0265x; 1.0024x over previous
//
#include <hip/hip_runtime.h>
#include <stdint.h>
#include <math.h>

// Problem constants (match reference)
#define EDGES 563200
#define NNODES 17600    // B*(NW+NS)
#define OUT0SZ 2640000  // 17600*150
#define MROWS 64000     // 1600 sentences * 40 positions
#define MPAD  64016     // + zero pad rows for window overhang
#define KSTRIDE 2112    // B pack row stride (halfs)

typedef _Float16 h2 __attribute__((ext_vector_type(2)));
typedef _Float16 h4 __attribute__((ext_vector_type(4)));
typedef _Float16 v8h __attribute__((ext_vector_type(8)));
typedef float v4f __attribute__((ext_vector_type(4)));

__device__ __forceinline__ float sigm(float x){ return 1.f / (1.f + expf(-x)); }

__device__ __forceinline__ float fdot2_(h2 a, h2 b, float c){
#if __has_builtin(__builtin_amdgcn_fdot2)
  return __builtin_amdgcn_fdot2(a, b, c, false);
#else
  return c + (float)a.x * (float)b.x + (float)a.y * (float)b.y;
#endif
}

// async global->LDS, 16B per lane; dest = wave-uniform base + lane*16
__device__ __forceinline__ void stage16(const char* g, char* lds_base, int lane){
#if __has_builtin(__builtin_amdgcn_global_load_lds)
  __builtin_amdgcn_global_load_lds(
      (const __attribute__((address_space(1))) void*)g,
      (__attribute__((address_space(3))) void*)lds_base, 16, 0, 0);
#else
  uint4 v = *(const uint4*)g;
  *(uint4*)(lds_base + lane * 16) = v;
#endif
}

// ---------------- merged prep: postab | bpack | whhpack x2 | zero x2 | embw |
// prep2 (sentlen+glen+rowmap, single block, fused as block 11300) ------------
__global__ __launch_bounds__(256)
void gcnk_mergedprep(float* __restrict__ pos,
                     const float* w2, const float* w3, const float* w4,
                     const float* w5, const float* w6, const float* w7,
                     const float* c2, const float* c3, const float* c4,
                     const float* c5, const float* c6, const float* c7,
                     _Float16* __restrict__ Bp, float* __restrict__ bias_p,
                     const float* __restrict__ whh0, _Float16* __restrict__ wpad0,
                     const float* __restrict__ whh1, _Float16* __restrict__ wpad1,
                     unsigned int* __restrict__ ngram_u, unsigned int* __restrict__ ecnt_u,
                     const int* __restrict__ x, const float* __restrict__ tab,
                     float4* __restrict__ out1,
                     const int* __restrict__ sx, int* __restrict__ sentlen,
                     int* __restrict__ glen_g, int* __restrict__ rowmap){
  int blk = blockIdx.x, tid = threadIdx.x;
  if (blk < 602){
    int idx = blk * 256 + tid;
    if (idx >= 513 * 300) return;
    int p = idx / 300, i = idx - p * 300;
    float v = 0.f;
    if (p != 0){
      double expo = (double)(2 * (i / 2)) / 300.0;
      double ang = (double)p / pow(10000.0, expo);
      v = (float)((i & 1) ? cos(ang) : sin(ang));
    }
    pos[idx] = v;
  } else if (blk < 3242){
    int idx = (blk - 602) * 256 + tid;
    if (idx < 2 * 160 * KSTRIDE){
      int n = idx / KSTRIDE, kk = idx - n * KSTRIDE;
      int g = n / 160, c = n - g * 160;
      _Float16 v = (_Float16)0.f;
      if (c < 150){
        int H = 3 * g + 2 + c / 50, o = c % 50;
        if (kk < 300 * H){
          const float* w;
          switch (H){ case 2: w = w2; break; case 3: w = w3; break;
                      case 4: w = w4; break; case 5: w = w5; break;
                      case 6: w = w6; break; default: w = w7; break; }
          v = (_Float16)w[o * 300 * H + kk];
        }
      }
      Bp[idx] = v;
    }
    if (idx < 320){
      int g = idx / 160, c = idx - g * 160;
      float bv = 0.f;
      if (c < 150){
        int H = 3 * g + 2 + c / 50, o = c % 50;
        const float* cbp;
        switch (H){ case 2: cbp = c2; break; case 3: cbp = c3; break;
                    case 4: cbp = c4; break; case 5: cbp = c5; break;
                    case 6: cbp = c6; break; default: cbp = c7; break; }
        bv = cbp[o];
      }
      bias_p[idx] = bv;
    }
  } else if (blk < 3955){
    int idx = (blk - 3242) * 256 + tid;
    if (idx >= 1200 * 152) return;
    int row = idx / 152, col = idx - row * 152;
    wpad0[idx] = (col < 150) ? (_Float16)whh0[row * 150 + col] : (_Float16)0.f;
  } else if (blk < 4668){
    int idx = (blk - 3955) * 256 + tid;
    if (idx >= 1200 * 152) return;
    int row = idx / 152, col = idx - row * 152;
    wpad1[idx] = (col < 150) ? (_Float16)whh1[row * 150 + col] : (_Float16)0.f;
  } else if (blk < 6543){
    int idx = (blk - 4668) * 256 + tid;
    if (idx < 1600 * 300) ngram_u[idx] = 0u;
  } else if (blk < 6612){
    int idx = (blk - 6543) * 256 + tid;
    if (idx < NNODES) ecnt_u[idx] = 0u;
  } else if (blk < 11300){
    int idx = (blk - 6612) * 256 + tid;
    if (idx >= 16000 * 75) return;
    int row = idx / 75, q = idx - row * 75;
    const float4* t = (const float4*)tab;
    out1[idx] = t[x[row] * 75 + q];
  } else {
    // prep2: sentlen + glen + rowmap (single block, 256 threads, uniform sync)
    __shared__ int sg[32];
    for (int i = tid; i < 1600; i += 256){
      int c = 0;
      for (int j = 0; j < 40; j++) c += (sx[i * 40 + j] != 0);
      sentlen[i] = c;
    }
    if (tid < 32){
      int c = 0;
      for (int s = 0; s < 50; s++) c += (sx[tid * 2000 + s * 40] != 0);
      glen_g[tid] = c; sg[tid] = c;
    }
    __syncthreads();
    for (int i = tid; i < 1600; i += 256){
      int b = i / 50, t2 = i - b * 50, g = sg[b];
      rowmap[i] = b * 50 + ((t2 < g) ? (g - 1 - t2) : t2);
    }
  }
}

// ---------------- enc (fp16): enc[m][d] = tab[tok]+pos, pad rows zero -------
__global__ void gcnk_ench(const int* __restrict__ sx, const float* __restrict__ tab,
                          const float* __restrict__ pos, const int* __restrict__ sentlen,
                          _Float16* __restrict__ ench){
  int idx = blockIdx.x * 256 + threadIdx.x;
  if (idx >= MPAD * 75) return;
  int row = idx / 75, q = idx - row * 75;
  int d = q * 4;
  h4 o; o[0] = (_Float16)0.f; o[1] = (_Float16)0.f; o[2] = (_Float16)0.f; o[3] = (_Float16)0.f;
  if (row < MROWS){
    int n = row / 40, l = row - n * 40;
    int tok = sx[n * 40 + l];
    int p = (l < sentlen[n]) ? (l + 1) : 0;
    float4 a = *(const float4*)(tab + (size_t)tok * 300 + d);
    float4 b = *(const float4*)(pos + (size_t)p * 300 + d);
    o[0] = (_Float16)(a.x + b.x); o[1] = (_Float16)(a.y + b.y);
    o[2] = (_Float16)(a.z + b.z); o[3] = (_Float16)(a.w + b.w);
  }
  *(h4*)(ench + (size_t)row * 300 + d) = o;
}

// ---------------- fused conv GEMM via MFMA f16 (r7 config: proven 118us) ----
// BM=128, BN=160, BK=64. global_load_lds(16B) with XOR-swizzled SOURCE
// (T2 + rule #21); ds_read_b128 applies the same XOR. Grid (500,2).
// Conv experiments closed: XCD swizzle (r8/r9) and 2-phase BK=32 dbuf (r11)
// all regressed — the barrier's implicit vmcnt(0) drains the prefetch too,
// so implicit 4-blocks/CU overlap is already optimal at HIP source level.
__global__ __launch_bounds__(256)
void gcnk_convmfma(const _Float16* __restrict__ A, const _Float16* __restrict__ Bp,
                   const float* __restrict__ bias_p, unsigned int* __restrict__ ngram_u){
  __shared__ __align__(1024) char smem[36864];
  _Float16* Asm = (_Float16*)smem;             // [128][64] halfs (128B/row)
  _Float16* Bsm = (_Float16*)(smem + 16384);   // [160][64] halfs
  float* Cs = (float*)smem;                    // epilogue reuse: [128][33]
  const int tid = threadIdx.x;
  const int m0 = blockIdx.x * 128;
  const int grp = blockIdx.y;
  const char* Abase = (const char*)A;
  const char* Bbase = (const char*)(Bp + (size_t)grp * 160 * KSTRIDE);
  const int kmax = grp ? 2112 : 1216;          // heads 2-4 need K<=1200
  const int w = tid >> 6, lane = tid & 63;
  const int wm = (w >> 1) * 64, wn = (w & 1) * 80;
  const int fm = lane & 15, fq = lane >> 4;
  const int lrow = lane >> 3;                              // 0..7
  const int loff = (((lane & 7) ^ lrow) << 4);             // swizzled src byte in 128B row

  v4f acc[4][5] = {};

  for (int kc = 0; kc < kmax; kc += 64){
    // stage A: 16 issues of 1KB (8 rows x 128B); wave w does issues 4w..4w+3
    #pragma unroll
    for (int ii = 0; ii < 4; ii++){
      int i = w * 4 + ii;
      const char* g = Abase + (size_t)(m0 + i * 8 + lrow) * 600 + kc * 2 + loff;
      stage16(g, (char*)Asm + i * 1024, lane);
    }
    // stage B: 20 issues; wave w does issues 5w..5w+4
    #pragma unroll
    for (int jj = 0; jj < 5; jj++){
      int j = w * 5 + jj;
      const char* g = Bbase + (size_t)(j * 8 + lrow) * (KSTRIDE * 2) + kc * 2 + loff;
      stage16(g, (char*)Bsm + j * 1024, lane);
    }
    __syncthreads();
    #pragma unroll
    for (int ks = 0; ks < 2; ks++){
      const int axor = (ks * 64 + fq * 16) ^ ((fm & 7) << 4);
      v8h af[4], bf[5];
      #pragma unroll
      for (int mt = 0; mt < 4; mt++)
        af[mt] = *(const v8h*)((const char*)Asm + (wm + mt * 16 + fm) * 128 + axor);
      #pragma unroll
      for (int nt = 0; nt < 5; nt++)
        bf[nt] = *(const v8h*)((const char*)Bsm + (wn + nt * 16 + fm) * 128 + axor);
      #pragma unroll
      for (int mt = 0; mt < 4; mt++)
        #pragma unroll
        for (int nt = 0; nt < 5; nt++)
          acc[mt][nt] = __builtin_amdgcn_mfma_f32_16x16x32_f16(af[mt], bf[nt], acc[mt][nt], 0, 0, 0);
    }
    __syncthreads();
  }

  // epilogue: 5 passes of 32 cols through LDS; relu+window-max -> atomicMax
  for (int p = 0; p < 5; p++){
    __syncthreads();
    #pragma unroll
    for (int nt = 0; nt < 5; nt++){
      int cstart = wn + nt * 16;
      if ((cstart >> 5) == p){
        int co = cstart - p * 32 + fm;
        #pragma unroll
        for (int mt = 0; mt < 4; mt++)
          #pragma unroll
          for (int r = 0; r < 4; r++)
            Cs[(wm + mt * 16 + fq * 4 + r) * 33 + co] = acc[mt][nt][r];
      }
    }
    __syncthreads();
    if (tid < 128){
      int cl = tid & 31, si = tid >> 5;        // 4 sentences can touch a 128-row tile
      int col = p * 32 + cl;                   // group-local col
      if (col < 150){
        int H = 3 * grp + 2 + col / 50, lh = 41 - H;
        int sent = m0 / 40 + si;
        if (sent < 1600){
          int rlo = sent * 40; if (rlo < m0) rlo = m0;
          int rhi = sent * 40 + lh; if (rhi > m0 + 128) rhi = m0 + 128;
          if (rlo < rhi){
            float bv = bias_p[grp * 160 + col];
            float vmax = 0.f;
            for (int r = rlo; r < rhi; r++){
              float v = Cs[(r - m0) * 33 + cl] + bv;
              vmax = fmaxf(vmax, v);
            }
            atomicMax(ngram_u + sent * 300 + grp * 150 + col, __float_as_uint(vmax));
          }
        }
      }
    }
  }
}

// ---------------- gc0 GEMM: A fp16 [M][300] -> C fp16 [M][160] + bias -------
__global__ __launch_bounds__(256)
void gcnk_mgemmH(const _Float16* __restrict__ Ah, const float* __restrict__ Wt,
                 const float* __restrict__ b1, _Float16* __restrict__ Ch, int M, int N){
  const int K = 300;
  __shared__ __align__(16) _Float16 As[128 * 40];
  __shared__ __align__(16) _Float16 Bs[64 * 40];
  const int tid = threadIdx.x;
  const int m0 = blockIdx.x * 128, n0 = blockIdx.y * 64;
  const int w = tid >> 6, lane = tid & 63;
  const int wm = (w >> 1) * 64, wn = (w & 1) * 32;
  const int fm = lane & 15, fq = lane >> 4;
  v4f acc[4][2] = {};
  for (int ch = 0; ch < 10; ch++){
    int kc = ch * 32;
    #pragma unroll
    for (int j = 0; j < 2; j++){            // A stage: 128 rows x 32 halfs
      int u = tid + 256 * j;
      int row = u >> 2, cb = (u & 3) * 8;
      int gm = m0 + row, gk = kc + cb;
      v8h vv;
      if (gm < M && gk + 8 <= K){
        const char* p = (const char*)(Ah + (size_t)gm * 300 + gk);
        union { uint2 u2[2]; v8h v; } t;
        t.u2[0] = *(const uint2*)p; t.u2[1] = *(const uint2*)(p + 8);
        vv = t.v;
      } else {
        #pragma unroll
        for (int e = 0; e < 8; e++)
          vv[e] = (gm < M && gk + e < K) ? Ah[(size_t)gm * 300 + gk + e] : (_Float16)0.f;
      }
      *(v8h*)(As + row * 40 + cb) = vv;
    }
    {                                        // B stage: 64 rows x 32 halfs (fp32 W)
      int row = tid >> 2, cb = (tid & 3) * 8;
      int gn = n0 + row, gk = kc + cb;
      v8h vv;
      if (gn < N && gk + 8 <= K){
        const float2* p = (const float2*)(Wt + (size_t)gn * K + gk);
        float2 q0 = p[0], q1 = p[1], q2 = p[2], q3 = p[3];
        vv[0] = (_Float16)q0.x; vv[1] = (_Float16)q0.y;
        vv[2] = (_Float16)q1.x; vv[3] = (_Float16)q1.y;
        vv[4] = (_Float16)q2.x; vv[5] = (_Float16)q2.y;
        vv[6] = (_Float16)q3.x; vv[7] = (_Float16)q3.y;
      } else {
        #pragma unroll
        for (int e = 0; e < 8; e++)
          vv[e] = (gn < N && gk + e < K) ? (_Float16)Wt[(size_t)gn * K + gk + e] : (_Float16)0.f;
      }
      *(v8h*)(Bs + row * 40 + cb) = vv;
    }
    __syncthreads();
    v8h af[4], bf[2];
    #pragma unroll
    for (int mt = 0; mt < 4; mt++)
      af[mt] = *(const v8h*)(As + (wm + mt * 16 + fm) * 40 + fq * 8);
    #pragma unroll
    for (int nt = 0; nt < 2; nt++)
      bf[nt] = *(const v8h*)(Bs + (wn + nt * 16 + fm) * 40 + fq * 8);
    #pragma unroll
    for (int mt = 0; mt < 4; mt++)
      #pragma unroll
      for (int nt = 0; nt < 2; nt++)
        acc[mt][nt] = __builtin_amdgcn_mfma_f32_16x16x32_f16(af[mt], bf[nt], acc[mt][nt], 0, 0, 0);
    __syncthreads();
  }
  #pragma unroll
  for (int nt = 0; nt < 2; nt++){
    int gn = n0 + wn + nt * 16 + fm;
    if (gn >= N) continue;
    float badd = b1[gn];
    #pragma unroll
    for (int mt = 0; mt < 4; mt++)
      #pragma unroll
      for (int r = 0; r < 4; r++){
        int gm = m0 + wm + mt * 16 + fq * 4 + r;
        if (gm < M) Ch[(size_t)gm * 160 + gn] = (_Float16)(acc[mt][nt][r] + badd);
      }
  }
}

// ---------------- gc1/gc2 GEMM: A fp16 [M][160](150 used) -> C fp16 [M][160]
__global__ __launch_bounds__(256)
void gcnk_mgemmHX(const _Float16* __restrict__ Ah, const float* __restrict__ Wt,
                  _Float16* __restrict__ Ch, int M){
  const int K = 150, N = 150;
  __shared__ __align__(16) _Float16 As[128 * 40];
  __shared__ __align__(16) _Float16 Bs[64 * 40];
  const int tid = threadIdx.x;
  const int m0 = blockIdx.x * 128, n0 = blockIdx.y * 64;
  const int w = tid >> 6, lane = tid & 63;
  const int wm = (w >> 1) * 64, wn = (w & 1) * 32;
  const int fm = lane & 15, fq = lane >> 4;
  v4f acc[4][2] = {};
  for (int ch = 0; ch < 5; ch++){          // ceil(150/32)=5 chunks
    int kc = ch * 32;
    #pragma unroll
    for (int j = 0; j < 2; j++){            // A stage: 128 rows x 32 halfs
      int u = tid + 256 * j;
      int row = u >> 2, cb = (u & 3) * 8;
      int gm = m0 + row, gk = kc + cb;
      v8h vv;
      if (gm < M && gk + 8 <= K){
        const char* p = (const char*)(Ah + (size_t)gm * 160 + gk);
        union { uint2 u2[2]; v8h v; } t;
        t.u2[0] = *(const uint2*)p; t.u2[1] = *(const uint2*)(p + 8);
        vv = t.v;
      } else {
        #pragma unroll
        for (int e = 0; e < 8; e++)
          vv[e] = (gm < M && gk + e < K) ? Ah[(size_t)gm * 160 + gk + e] : (_Float16)0.f;
      }
      *(v8h*)(As + row * 40 + cb) = vv;
    }
    {                                        // B stage: 64 rows x 32 halfs (fp32 W)
      int row = tid >> 2, cb = (tid & 3) * 8;
      int gn = n0 + row, gk = kc + cb;
      v8h vv;
      if (gn < N && gk + 8 <= K){
        const float2* p = (const float2*)(Wt + (size_t)gn * K + gk);
        float2 q0 = p[0], q1 = p[1], q2 = p[2], q3 = p[3];
        vv[0] = (_Float16)q0.x; vv[1] = (_Float16)q0.y;
        vv[2] = (_Float16)q1.x; vv[3] = (_Float16)q1.y;
        vv[4] = (_Float16)q2.x; vv[5] = (_Float16)q2.y;
        vv[6] = (_Float16)q3.x; vv[7] = (_Float16)q3.y;
      } else {
        #pragma unroll
        for (int e = 0; e < 8; e++)
          vv[e] = (gn < N && gk + e < K) ? (_Float16)Wt[(size_t)gn * K + gk + e] : (_Float16)0.f;
      }
      *(v8h*)(Bs + row * 40 + cb) = vv;
    }
    __syncthreads();
    v8h af[4], bf[2];
    #pragma unroll
    for (int mt = 0; mt < 4; mt++)
      af[mt] = *(const v8h*)(As + (wm + mt * 16 + fm) * 40 + fq * 8);
    #pragma unroll
    for (int nt = 0; nt < 2; nt++)
      bf[nt] = *(const v8h*)(Bs + (wn + nt * 16 + fm) * 40 + fq * 8);
    #pragma unroll
    for (int mt = 0; mt < 4; mt++)
      #pragma unroll
      for (int nt = 0; nt < 2; nt++)
        acc[mt][nt] = __builtin_amdgcn_mfma_f32_16x16x32_f16(af[mt], bf[nt], acc[mt][nt], 0, 0, 0);
    __syncthreads();
  }
  #pragma unroll
  for (int nt = 0; nt < 2; nt++){
    int gn = n0 + wn + nt * 16 + fm;
    if (gn >= N) continue;
    #pragma unroll
    for (int mt = 0; mt < 4; mt++)
      #pragma unroll
      for (int r = 0; r < 4; r++){
        int gm = m0 + wm + mt * 16 + fq * 4 + r;
        if (gm < M) Ch[(size_t)gm * 160 + gn] = (_Float16)acc[mt][nt][r];
      }
  }
}

// ---------------- flexible small GEMM with fused gather/concat/mask/pos -----
__global__ __launch_bounds__(256)
void gcnk_mgemmF(const float* __restrict__ A1, const int* __restrict__ mapA,
                 const float* __restrict__ A2, const int* __restrict__ mapB,
                 const int* __restrict__ glen, int usemask,
                 const float* __restrict__ apos,
                 const float* __restrict__ Wt, const float* __restrict__ b1,
                 const float* __restrict__ b2, float* __restrict__ C,
                 int M, int N, int K){
  const int BM = 64, WMT = 2, WNT = 2;
  __shared__ __align__(16) _Float16 As[BM * 40];
  __shared__ __align__(16) _Float16 Bs[64 * 40];
  const int tid = threadIdx.x;
  const int m0 = blockIdx.x * BM, n0 = blockIdx.y * 64;
  const int w = tid >> 6, lane = tid & 63;
  const int wm = (w >> 1) * (WMT * 16), wn = (w & 1) * (WNT * 16);
  const int fm = lane & 15, fq = lane >> 4;
  v4f acc[WMT][WNT] = {};
  const int nch = (K + 31) >> 5;
  for (int ch = 0; ch < nch; ch++){
    int kc = ch * 32;
    {                                        // A stage: 64 rows x 32 halfs
      int row = tid >> 2, cb = (tid & 3) * 8;
      int gm = m0 + row, gk = kc + cb;
      v8h vv;
      bool ok = (gm < M);
      if (ok && usemask){
        int b = gm / 50;
        if (gm - b * 50 >= glen[b]) ok = false;
      }
      if (!ok){
        #pragma unroll
        for (int e = 0; e < 8; e++) vv[e] = (_Float16)0.f;
      } else if (!A2){
        int r = mapA ? mapA[gm] : gm;
        const float* base = A1 + (size_t)r * K;
        if (gk + 8 <= K){
          const float2* p = (const float2*)(base + gk);
          float2 q0 = p[0], q1 = p[1], q2 = p[2], q3 = p[3];
          if (apos){
            const float2* a2 = (const float2*)(apos + (size_t)(gm % 50) * K + gk);
            float2 r0 = a2[0], r1 = a2[1], r2 = a2[2], r3 = a2[3];
            q0.x += r0.x; q0.y += r0.y; q1.x += r1.x; q1.y += r1.y;
            q2.x += r2.x; q2.y += r2.y; q3.x += r3.x; q3.y += r3.y;
          }
          vv[0] = (_Float16)q0.x; vv[1] = (_Float16)q0.y;
          vv[2] = (_Float16)q1.x; vv[3] = (_Float16)q1.y;
          vv[4] = (_Float16)q2.x; vv[5] = (_Float16)q2.y;
          vv[6] = (_Float16)q3.x; vv[7] = (_Float16)q3.y;
        } else {
          #pragma unroll
          for (int e = 0; e < 8; e++){
            int c = gk + e;
            float vf = (c < K) ? base[c] : 0.f;
            if (apos && c < K) vf += apos[(size_t)(gm % 50) * K + c];
            vv[e] = (_Float16)vf;
          }
        }
      } else {
        int rA = mapA ? mapA[gm] : gm;
        int rB = mapB ? mapB[gm] : gm;
        const float* pa = A1 + (size_t)rA * 150;
        const float* pb = A2 + (size_t)rB * 150;
        if (gk + 8 <= 150){
          const float2* p = (const float2*)(pa + gk);
          float2 q0 = p[0], q1 = p[1], q2 = p[2], q3 = p[3];
          vv[0] = (_Float16)q0.x; vv[1] = (_Float16)q0.y;
          vv[2] = (_Float16)q1.x; vv[3] = (_Float16)q1.y;
          vv[4] = (_Float16)q2.x; vv[5] = (_Float16)q2.y;
          vv[6] = (_Float16)q3.x; vv[7] = (_Float16)q3.y;
        } else if (gk >= 152 && gk + 8 <= K){
          const float2* p = (const float2*)(pb + gk - 150);
          float2 q0 = p[0], q1 = p[1], q2 = p[2], q3 = p[3];
          vv[0] = (_Float16)q0.x; vv[1] = (_Float16)q0.y;
          vv[2] = (_Float16)q1.x; vv[3] = (_Float16)q1.y;
          vv[4] = (_Float16)q2.x; vv[5] = (_Float16)q2.y;
          vv[6] = (_Float16)q3.x; vv[7] = (_Float16)q3.y;
        } else {
          #pragma unroll
          for (int e = 0; e < 8; e++){
            int c = gk + e;
            vv[e] = (c < 150) ? (_Float16)pa[c]
                  : ((c < K) ? (_Float16)pb[c - 150] : (_Float16)0.f);
          }
        }
      }
      *(v8h*)(As + row * 40 + cb) = vv;
    }
    {                                        // B stage: 64 rows x 32 halfs
      int row = tid >> 2, cb = (tid & 3) * 8;
      int gn = n0 + row, gk = kc + cb;
      v8h vv;
      if (gn < N && gk + 8 <= K){
        const float2* p = (const float2*)(Wt + (size_t)gn * K + gk);
        float2 q0 = p[0], q1 = p[1], q2 = p[2], q3 = p[3];
        vv[0] = (_Float16)q0.x; vv[1] = (_Float16)q0.y;
        vv[2] = (_Float16)q1.x; vv[3] = (_Float16)q1.y;
        vv[4] = (_Float16)q2.x; vv[5] = (_Float16)q2.y;
        vv[6] = (_Float16)q3.x; vv[7] = (_Float16)q3.y;
      } else {
        #pragma unroll
        for (int e = 0; e < 8; e++)
          vv[e] = (gn < N && gk + e < K) ? (_Float16)Wt[(size_t)gn * K + gk + e] : (_Float16)0.f;
      }
      *(v8h*)(Bs + row * 40 + cb) = vv;
    }
    __syncthreads();
    v8h af[WMT], bf[WNT];
    #pragma unroll
    for (int mt = 0; mt < WMT; mt++)
      af[mt] = *(const v8h*)(As + (wm + mt * 16 + fm) * 40 + fq * 8);
    #pragma unroll
    for (int nt = 0; nt < WNT; nt++)
      bf[nt] = *(const v8h*)(Bs + (wn + nt * 16 + fm) * 40 + fq * 8);
    #pragma unroll
    for (int mt = 0; mt < WMT; mt++)
      #pragma unroll
      for (int nt = 0; nt < WNT; nt++)
        acc[mt][nt] = __builtin_amdgcn_mfma_f32_16x16x32_f16(af[mt], bf[nt], acc[mt][nt], 0, 0, 0);
    __syncthreads();
  }
  #pragma unroll
  for (int nt = 0; nt < WNT; nt++){
    int gn = n0 + wn + nt * 16 + fm;
    if (gn >= N) continue;
    float badd = (b1 ? b1[gn] : 0.f) + (b2 ? b2[gn] : 0.f);
    #pragma unroll
    for (int mt = 0; mt < WMT; mt++)
      #pragma unroll
      for (int r = 0; r < 4; r++){
        int gm = m0 + wm + mt * 16 + fq * 4 + r;
        if (gm < M) C[(size_t)gm * N + gn] = acc[mt][nt][r] + badd;
      }
  }
}

// ---------------- paired variant: blockIdx.z selects one of two param sets --
struct FArgs {
  const float* A1; const int* mapA;
  const float* A2; const int* mapB;
  const float* Wt; const float* b1; const float* b2;
  float* C;
};

__global__ __launch_bounds__(256)
void gcnk_mgemmF2(FArgs pa, FArgs pb, int M, int N, int K){
  const int BM = 64, WMT = 2, WNT = 2;
  __shared__ __align__(16) _Float16 As[BM * 40];
  __shared__ __align__(16) _Float16 Bs[64 * 40];
  const FArgs P = blockIdx.z ? pb : pa;
  const int tid = threadIdx.x;
  const int m0 = blockIdx.x * BM, n0 = blockIdx.y * 64;
  const int w = tid >> 6, lane = tid & 63;
  const int wm = (w >> 1) * (WMT * 16), wn = (w & 1) * (WNT * 16);
  const int fm = lane & 15, fq = lane >> 4;
  v4f acc[WMT][WNT] = {};
  const int nch = (K + 31) >> 5;
  for (int ch = 0; ch < nch; ch++){
    int kc = ch * 32;
    {                                        // A stage: 64 rows x 32 halfs
      int row = tid >> 2, cb = (tid & 3) * 8;
      int gm = m0 + row, gk = kc + cb;
      v8h vv;
      if (gm >= M){
        #pragma unroll
        for (int e = 0; e < 8; e++) vv[e] = (_Float16)0.f;
      } else if (!P.A2){
        int r = P.mapA ? P.mapA[gm] : gm;
        const float* base = P.A1 + (size_t)r * K;
        if (gk + 8 <= K){
          const float2* p = (const float2*)(base + gk);
          float2 q0 = p[0], q1 = p[1], q2 = p[2], q3 = p[3];
          vv[0] = (_Float16)q0.x; vv[1] = (_Float16)q0.y;
          vv[2] = (_Float16)q1.x; vv[3] = (_Float16)q1.y;
          vv[4] = (_Float16)q2.x; vv[5] = (_Float16)q2.y;
          vv[6] = (_Float16)q3.x; vv[7] = (_Float16)q3.y;
        } else {
          #pragma unroll
          for (int e = 0; e < 8; e++)
            vv[e] = (gk + e < K) ? (_Float16)base[gk + e] : (_Float16)0.f;
        }
      } else {
        int rA = P.mapA ? P.mapA[gm] : gm;
        int rB = P.mapB ? P.mapB[gm] : gm;
        const float* paa = P.A1 + (size_t)rA * 150;
        const float* pbb = P.A2 + (size_t)rB * 150;
        if (gk + 8 <= 150){
          const float2* p = (const float2*)(paa + gk);
          float2 q0 = p[0], q1 = p[1], q2 = p[2], q3 = p[3];
          vv[0] = (_Float16)q0.x; vv[1] = (_Float16)q0.y;
          vv[2] = (_Float16)q1.x; vv[3] = (_Float16)q1.y;
          vv[4] = (_Float16)q2.x; vv[5] = (_Float16)q2.y;
          vv[6] = (_Float16)q3.x; vv[7] = (_Float16)q3.y;
        } else if (gk >= 152 && gk + 8 <= K){
          const float2* p = (const float2*)(pbb + gk - 150);
          float2 q0 = p[0], q1 = p[1], q2 = p[2], q3 = p[3];
          vv[0] = (_Float16)q0.x; vv[1] = (_Float16)q0.y;
          vv[2] = (_Float16)q1.x; vv[3] = (_Float16)q1.y;
          vv[4] = (_Float16)q2.x; vv[5] = (_Float16)q2.y;
          vv[6] = (_Float16)q3.x; vv[7] = (_Float16)q3.y;
        } else {
          #pragma unroll
          for (int e = 0; e < 8; e++){
            int c = gk + e;
            vv[e] = (c < 150) ? (_Float16)paa[c]
                  : ((c < K) ? (_Float16)pbb[c - 150] : (_Float16)0.f);
          }
        }
      }
      *(v8h*)(As + row * 40 + cb) = vv;
    }
    {                                        // B stage: 64 rows x 32 halfs
      int row = tid >> 2, cb = (tid & 3) * 8;
      int gn = n0 + row, gk = kc + cb;
      v8h vv;
      if (gn < N && gk + 8 <= K){
        const float2* p = (const float2*)(P.Wt + (size_t)gn * K + gk);
        float2 q0 = p[0], q1 = p[1], q2 = p[2], q3 = p[3];
        vv[0] = (_Float16)q0.x; vv[1] = (_Float16)q0.y;
        vv[2] = (_Float16)q1.x; vv[3] = (_Float16)q1.y;
        vv[4] = (_Float16)q2.x; vv[5] = (_Float16)q2.y;
        vv[6] = (_Float16)q3.x; vv[7] = (_Float16)q3.y;
      } else {
        #pragma unroll
        for (int e = 0; e < 8; e++)
          vv[e] = (gn < N && gk + e < K) ? (_Float16)P.Wt[(size_t)gn * K + gk + e] : (_Float16)0.f;
      }
      *(v8h*)(Bs + row * 40 + cb) = vv;
    }
    __syncthreads();
    v8h af[WMT], bf[WNT];
    #pragma unroll
    for (int mt = 0; mt < WMT; mt++)
      af[mt] = *(const v8h*)(As + (wm + mt * 16 + fm) * 40 + fq * 8);
    #pragma unroll
    for (int nt = 0; nt < WNT; nt++)
      bf[nt] = *(const v8h*)(Bs + (wn + nt * 16 + fm) * 40 + fq * 8);
    #pragma unroll
    for (int mt = 0; mt < WMT; mt++)
      #pragma unroll
      for (int nt = 0; nt < WNT; nt++)
        acc[mt][nt] = __builtin_amdgcn_mfma_f32_16x16x32_f16(af[mt], bf[nt], acc[mt][nt], 0, 0, 0);
    __syncthreads();
  }
  #pragma unroll
  for (int nt = 0; nt < WNT; nt++){
    int gn = n0 + wn + nt * 16 + fm;
    if (gn >= N) continue;
    float badd = (P.b1 ? P.b1[gn] : 0.f) + (P.b2 ? P.b2[gn] : 0.f);
    #pragma unroll
    for (int mt = 0; mt < WMT; mt++)
      #pragma unroll
      for (int r = 0; r < 4; r++){
        int gm = m0 + wm + mt * 16 + fq * 4 + r;
        if (gm < M) P.C[(size_t)gm * N + gn] = acc[mt][nt][r] + badd;
      }
  }
}

// ---------------- node feature assembly, fp16 out [17600 x 300] -------------
__global__ void gcnk_nodes_in_h(const int* __restrict__ x, const float* __restrict__ tab,
                                const float* __restrict__ cnnf, const float* __restrict__ lstmf,
                                h2* __restrict__ out){
  int idx = blockIdx.x * 256 + threadIdx.x;
  if (idx >= NNODES * 150) return;
  int nrow = idx / 150, q = idx - nrow * 150;
  int d = q * 2;
  int b = nrow / 550, j = nrow - b * 550;
  float2 v;
  if (j < 500) v = *(const float2*)(tab + (size_t)x[b * 500 + j] * 300 + d);
  else {
    int r = b * 50 + (j - 500);
    if (d < 150) v = *(const float2*)(cnnf + (size_t)r * 150 + d);
    else         v = *(const float2*)(lstmf + (size_t)r * 150 + d - 150);
  }
  h2 o; o[0] = (_Float16)v.x; o[1] = (_Float16)v.y;
  out[idx] = o;
}

// ---------------- LSTM recurrence: weights in VGPRs, h fp16 in LDS ----------
__global__ __launch_bounds__(640)
void gcnk_lstm(const float* __restrict__ xf, const float* __restrict__ xr,
               const _Float16* __restrict__ wpad, float* __restrict__ fo,
               float* __restrict__ ro){
  int b = blockIdx.x >> 1, dir = blockIdx.x & 1;
  const float* xih = dir ? xr : xf;
  float* out = dir ? ro : fo;
  __shared__ __align__(16) _Float16 hh[160];
  __shared__ float gates[600];
  const int tid = threadIdx.x;

  h2 w[76];
  if (tid < 600){
    const h2* wrow = (const h2*)(wpad + ((size_t)dir * 600 + tid) * 152);
    #pragma unroll
    for (int j = 0; j < 76; j++) w[j] = wrow[j];
  }
  for (int u = tid; u < 160; u += 640) hh[u] = (_Float16)0.f;
  float creg = 0.f;
  __syncthreads();

  for (int t = 0; t < 50; t++){
    if (tid < 600){
      float acc = xih[(b * 50 + t) * 600 + tid];
      float a0 = 0.f, a1 = 0.f, a2 = 0.f, a3 = 0.f;   // break the dep chain 4-way
      #pragma unroll
      for (int j = 0; j < 19; j++){
        union { float4 f; h2 h[4]; } u;
        u.f = *(const float4*)(hh + j * 8);
        a0 = fdot2_(w[4 * j + 0], u.h[0], a0);
        a1 = fdot2_(w[4 * j + 1], u.h[1], a1);
        a2 = fdot2_(w[4 * j + 2], u.h[2], a2);
        a3 = fdot2_(w[4 * j + 3], u.h[3], a3);
      }
      gates[tid] = acc + ((a0 + a1) + (a2 + a3));
    }
    __syncthreads();
    if (tid < 150){
      float ig = sigm(gates[tid]);
      float fg = sigm(gates[150 + tid]);
      float gg = tanhf(gates[300 + tid]);
      float og = sigm(gates[450 + tid]);
      creg = fg * creg + ig * gg;
      float hn = og * tanhf(creg);
      hh[tid] = (_Float16)hn;
      out[(b * 50 + t) * 150 + tid] = hn;
    }
    __syncthreads();
  }
}

// ---------------- GCN: CSR build (counting sort by dst) ---------------------
__global__ void gcnk_hist(const int* __restrict__ ei, int* __restrict__ ecnt){
  int e = blockIdx.x * 256 + threadIdx.x;
  if (e < EDGES) atomicAdd(&ecnt[ei[EDGES + e]], 1);
}

// fast single-block scan: serial 18/thread + wave shfl scan + 16-entry scan
// also emits dis[i] = rsqrt(deg+1) (fused dis2)
__global__ __launch_bounds__(1024)
void gcnk_scan(const int* __restrict__ ecnt, int* __restrict__ eoff,
               int* __restrict__ ecur, float* __restrict__ dis){
  __shared__ int wsum[16];
  int tid = threadIdx.x;
  int base = tid * 18;
  int pre[18];
  int s = 0;
  #pragma unroll
  for (int i = 0; i < 18; i++){
    int idx = base + i;
    int c = (idx < NNODES) ? ecnt[idx] : 0;
    if (idx < NNODES) dis[idx] = rsqrtf((float)(c + 1));
    pre[i] = s; s += c;
  }
  int lane = tid & 63, wid = tid >> 6;
  int run = s;
  #pragma unroll
  for (int off = 1; off < 64; off <<= 1){
    int y = __shfl_up(run, off, 64);
    if (lane >= off) run += y;
  }
  if (lane == 63) wsum[wid] = run;
  __syncthreads();
  if (tid == 0){
    int a = 0;
    #pragma unroll
    for (int i = 0; i < 16; i++){ int t2 = wsum[i]; wsum[i] = a; a += t2; }
  }
  __syncthreads();
  int excl = wsum[wid] + run - s;
  #pragma unroll
  for (int i = 0; i < 18; i++){
    int idx = base + i;
    if (idx < NNODES){
      int e = excl + pre[i];
      eoff[idx] = e; ecur[idx] = e;
    }
  }
}

__global__ void gcnk_scatter(const int* __restrict__ ei, int* __restrict__ ecur,
                             int* __restrict__ esrc){
  int e = blockIdx.x * 256 + threadIdx.x;
  if (e < EDGES){
    int d = ei[EDGES + e];
    int p = atomicAdd(&ecur[d], 1);
    esrc[p] = ei[e];
  }
}

// ---------------- GCN aggregation: fp16 gather + fused bias/elu epilogue ----
// 3 dsts per 256-thread block: thread t -> group g=t/75 (dst), elem e=t%75.
// outh=1: write fp16 [d][160]; outh=0: write fp32 [d][150].
__global__ __launch_bounds__(256)
void gcnk_aggcsr_h(const int* __restrict__ eoff, const int* __restrict__ ecnt,
                   const int* __restrict__ esrc, const float* __restrict__ dis,
                   const _Float16* __restrict__ xw, const float* __restrict__ bias,
                   void* __restrict__ out, int doelu, int outh){
  int t = threadIdx.x;
  if (t >= 225) return;
  int g = t / 75, e = t - g * 75;
  int d = blockIdx.x * 3 + g;
  if (d >= NNODES) return;
  float dd = dis[d];
  float ax0, ay0, ax1 = 0.f, ay1 = 0.f;
  {
    h2 v = *(const h2*)(xw + (size_t)d * 160 + 2 * e);
    ax0 = (float)v[0] * dd; ay0 = (float)v[1] * dd;
  }
  int beg = eoff[d], end = beg + ecnt[d];
  int j = beg;
  for (; j + 1 < end; j += 2){
    int s0 = esrc[j], s1 = esrc[j + 1];
    float d0 = dis[s0], d1 = dis[s1];
    h2 v0 = *(const h2*)(xw + (size_t)s0 * 160 + 2 * e);
    h2 v1 = *(const h2*)(xw + (size_t)s1 * 160 + 2 * e);
    ax0 += (float)v0[0] * d0; ay0 += (float)v0[1] * d0;
    ax1 += (float)v1[0] * d1; ay1 += (float)v1[1] * d1;
  }
  if (j < end){
    int s = esrc[j];
    float ds_ = dis[s];
    h2 v = *(const h2*)(xw + (size_t)s * 160 + 2 * e);
    ax0 += (float)v[0] * ds_; ay0 += (float)v[1] * ds_;
  }
  float o0 = (ax0 + ax1) * dd + bias[2 * e];
  float o1 = (ay0 + ay1) * dd + bias[2 * e + 1];
  if (doelu){
    o0 = (o0 > 0.f) ? o0 : expm1f(o0);
    o1 = (o1 > 0.f) ? o1 : expm1f(o1);
  }
  if (outh){
    h2 o; o[0] = (_Float16)o0; o[1] = (_Float16)o1;
    *(h2*)((_Float16*)out + (size_t)d * 160 + 2 * e) = o;
  } else {
    *(float2*)((float*)out + (size_t)d * 150 + 2 * e) = make_float2(o0, o1);
  }
}

// ============================================================================
extern "C" void kernel_launch(void* const* d_in, const int* in_sizes, int n_in,
                              void* d_out, int out_size, void* d_ws, size_t ws_size,
                              hipStream_t stream){
  (void)in_sizes; (void)n_in; (void)out_size; (void)ws_size;

  char* wsb = (char*)d_ws;
  size_t off = 0;
  auto alloc = [&](size_t bytes) -> void* {
    void* p = wsb + off;
    off = (off + bytes + 255) & ~(size_t)255;
    return p;
  };
  float* pos_tab  = (float*)alloc(513 * 300 * 4);
  int*   sentlen  = (int*)alloc(1600 * 4);
  int*   glen     = (int*)alloc(32 * 4);
  int*   rowmap   = (int*)alloc(1600 * 4);
  float* ngram    = (float*)alloc(1600 * 300 * 4);
  float* cnn_feat = (float*)alloc(1600 * 150 * 4);
  float* xih_f    = (float*)alloc(1600 * 600 * 4);
  float* xih_r    = (float*)alloc(1600 * 600 * 4);
  float* f0       = (float*)alloc(1600 * 150 * 4);
  float* r0       = (float*)alloc(1600 * 150 * 4);
  float* f1       = (float*)alloc(1600 * 150 * 4);
  float* r1       = (float*)alloc(1600 * 150 * 4);
  float* lstm_ft  = (float*)alloc(1600 * 150 * 4);
  h2*    nodes_ih = (h2*)alloc((size_t)NNODES * 150 * 4);   // fp16 [NNODES][300]
  _Float16* nodesh= (_Float16*)alloc((size_t)NNODES * 160 * 2); // fp16 [NNODES][160]
  float* dis      = (float*)alloc(NNODES * 4);
  _Float16* xwh   = (_Float16*)alloc((size_t)NNODES * 160 * 2);
  _Float16* ench  = (_Float16*)alloc((size_t)MPAD * 300 * 2);
  _Float16* Bp    = (_Float16*)alloc((size_t)2 * 160 * KSTRIDE * 2);
  float* bias_p   = (float*)alloc(320 * 4);
  _Float16* wpad0 = (_Float16*)alloc(1200 * 152 * 2);
  _Float16* wpad1 = (_Float16*)alloc(1200 * 152 * 2);
  int*   ecnt     = (int*)alloc(NNODES * 4);
  int*   eoff     = (int*)alloc(NNODES * 4);
  int*   ecur     = (int*)alloc(NNODES * 4);
  int*   esrc     = (int*)alloc(EDGES * 4);

  const int*   x   = (const int*)d_in[0];
  const int*   sx  = (const int*)d_in[1];
  const int*   ei  = (const int*)d_in[2];
  const float* tab = (const float*)d_in[3];
  const float *cw[6], *cb[6];
  for (int h = 0; h < 6; h++){ cw[h] = (const float*)d_in[4 + 2 * h]; cb[h] = (const float*)d_in[5 + 2 * h]; }
  const float* cnnw = (const float*)d_in[16]; const float* cnnb = (const float*)d_in[17];
  const float* wih0 = (const float*)d_in[18]; const float* whh0 = (const float*)d_in[19];
  const float* bih0 = (const float*)d_in[20]; const float* bhh0 = (const float*)d_in[21];
  const float* wih1 = (const float*)d_in[22]; const float* whh1 = (const float*)d_in[23];
  const float* bih1 = (const float*)d_in[24]; const float* bhh1 = (const float*)d_in[25];
  const float* lpw  = (const float*)d_in[26]; const float* lpb  = (const float*)d_in[27];
  const float* g0w  = (const float*)d_in[28]; const float* g0b  = (const float*)d_in[29];
  const float* g1w  = (const float*)d_in[30]; const float* g1b  = (const float*)d_in[31];
  const float* g2w  = (const float*)d_in[32]; const float* g2b  = (const float*)d_in[33];

  float* out0 = (float*)d_out;
  float4* out1 = (float4*)((float*)d_out + OUT0SZ);

  // flexible small GEMM (M=1600)
  auto mgemmF = [&](const float* A1, const int* mapA, const float* A2, const int* mapB,
                    const int* gl, int um, const float* apos, const float* W,
                    const float* b1, const float* b2, float* C, int N, int K){
    dim3 g(25, (N + 63) / 64);
    gcnk_mgemmF<<<g, 256, 0, stream>>>(A1, mapA, A2, mapB, gl, um, apos, W, b1, b2, C, 1600, N, K);
  };

  // ---- pipeline ----
  gcnk_mergedprep<<<11301, 256, 0, stream>>>(
      pos_tab, cw[0], cw[1], cw[2], cw[3], cw[4], cw[5],
      cb[0], cb[1], cb[2], cb[3], cb[4], cb[5], Bp, bias_p,
      whh0, wpad0, whh1, wpad1, (unsigned int*)ngram, (unsigned int*)ecnt,
      x, tab, out1, sx, sentlen, glen, rowmap);
  gcnk_ench<<<(MPAD * 75 + 255) / 256, 256, 0, stream>>>(sx, tab, pos_tab, sentlen, ench);

  // conv: r7 config (proven fastest), 2-D grid
  {
    dim3 g(500, 2);
    gcnk_convmfma<<<g, 256, 0, stream>>>(ench, Bp, bias_p, (unsigned int*)ngram);
  }

  // cnn_proj with POS-add fused into A-stage
  mgemmF(ngram, nullptr, nullptr, nullptr, nullptr, 0, pos_tab,
         cnnw, cnnb, nullptr, cnn_feat, 150, 300);

  // BiLSTM layer 0: fwd+rev xih in ONE z=2 launch (permute fused into A-load)
  {
    FArgs pa{cnn_feat, nullptr, nullptr, nullptr, wih0,             bih0,       bhh0,       xih_f};
    FArgs pb{cnn_feat, rowmap,  nullptr, nullptr, wih0 + 600 * 150, bih0 + 600, bhh0 + 600, xih_r};
    dim3 g(25, 10, 2);
    gcnk_mgemmF2<<<g, 256, 0, stream>>>(pa, pb, 1600, 600, 150);
  }
  gcnk_lstm<<<64, 640, 0, stream>>>(xih_f, xih_r, wpad0, f0, r0);

  // BiLSTM layer 1: fwd+rev xih in ONE z=2 launch (concat fused into A-load)
  {
    FArgs pa{f0, nullptr, r0, rowmap,  wih1,             bih1,       bhh1,       xih_f};
    FArgs pb{f0, rowmap,  r0, nullptr, wih1 + 600 * 300, bih1 + 600, bhh1 + 600, xih_r};
    dim3 g(25, 10, 2);
    gcnk_mgemmF2<<<g, 256, 0, stream>>>(pa, pb, 1600, 600, 300);
  }
  gcnk_lstm<<<64, 640, 0, stream>>>(xih_f, xih_r, wpad1, f1, r1);

  // masked projection (concat + mask fused into A-load)
  mgemmF(f1, nullptr, r1, rowmap, glen, 1, nullptr, lpw, lpb, nullptr, lstm_ft, 150, 300);

  // node features (fp16, gathered once) + gc0 (fp16-A GEMM -> fp16 nodesh)
  gcnk_nodes_in_h<<<(NNODES * 150 + 255) / 256, 256, 0, stream>>>(x, tab, cnn_feat, lstm_ft, nodes_ih);
  {
    dim3 g(138, 3);
    gcnk_mgemmH<<<g, 256, 0, stream>>>((const _Float16*)nodes_ih, g0w, g0b, nodesh, NNODES, 150);
  }

  // CSR build (once, reused by both GCN layers); dis fused into scan
  gcnk_hist<<<2200, 256, 0, stream>>>(ei, ecnt);
  gcnk_scan<<<1, 1024, 0, stream>>>(ecnt, eoff, ecur, dis);
  gcnk_scatter<<<2200, 256, 0, stream>>>(ei, ecur, esrc);

  // gc1 + elu (fp16 A, fp16 xw gather, fused bias+elu epilogue -> fp16 nodesh)
  {
    dim3 g(138, 3);
    gcnk_mgemmHX<<<g, 256, 0, stream>>>(nodesh, g1w, xwh, NNODES);
  }
  gcnk_aggcsr_h<<<(NNODES + 2) / 3, 256, 0, stream>>>(eoff, ecnt, esrc, dis, xwh, g1b, nodesh, 1, 1);

  // gc2 -> output 0 (fp16 A, fused bias epilogue -> fp32 out0)
  {
    dim3 g(138, 3);
    gcnk_mgemmHX<<<g, 256, 0, stream>>>(nodesh, g2w, xwh, NNODES);
  }
  gcnk_aggcsr_h<<<(NNODES + 2) / 3, 256, 0, stream>>>(eoff, ecnt, esrc, dis, xwh, g2b, out0, 0, 0);
}